// Round 9
// baseline (253.975 us; speedup 1.0000x reference)
//
#include <hip/hip_runtime.h>

#define NN 50000
#define NE 1600000
#define NBA 128          // pass-A edge chunks (blocks)
#define CPB (NE / NBA)   // 12500 edges per chunk
#define NBUCK 196        // dst>>8 buckets (256 nodes each); 49999>>8 = 195
#define MAXBE 12288      // per-bucket edge cap: mean 8192, sigma~90 -> +45 sigma
#define SEGCAP 10240     // agg LDS csr ints (40 KB): mean 8192 +22 sigma

typedef unsigned int uint;
typedef __attribute__((ext_vector_type(8))) short short8;   // 8 bf16 (4 VGPRs)
typedef __attribute__((ext_vector_type(4))) float f32x4;    // MFMA accumulator

// All node-feature buffers are CHUNK-MAJOR bf16: plane c (16 feats = 32 B/row)
// at [(c*NN + n)*2] uint4s. 1.6 MB/plane -> fits one XCD L2. h2 for fc is the
// same layout (fc adapts). chunk = blockIdx.x & 7 exploits bid%8 XCD round-robin.

// ---------------- bf16 helpers (packed pairs in uint32) ----------------

__device__ __forceinline__ uint bf16rne(float f) {
  uint u = __float_as_uint(f);
  return (u + 0x7fffu + ((u >> 16) & 1u)) >> 16;
}
__device__ __forceinline__ uint packbf2(float lo, float hi) {
  return bf16rne(lo) | (bf16rne(hi) << 16);
}
__device__ __forceinline__ float bflo(uint u) { return __uint_as_float(u << 16); }
__device__ __forceinline__ float bfhi(uint u) { return __uint_as_float(u & 0xffff0000u); }

__device__ __forceinline__ short8 as_short8(uint4 v) {
  union { uint4 u; short8 s; } cv; cv.u = v; return cv.s;
}

__device__ __forceinline__ void add8(const uint4 v, float* a) {
  a[0] += bflo(v.x); a[1] += bfhi(v.x);
  a[2] += bflo(v.y); a[3] += bfhi(v.y);
  a[4] += bflo(v.z); a[5] += bfhi(v.z);
  a[6] += bflo(v.w); a[7] += bfhi(v.w);
}

// f32 row-major [N][128] -> chunk-major bf16. grid (196, 8).
__global__ __launch_bounds__(256) void tobf16c_kernel(const float* __restrict__ in,
                                                      uint* __restrict__ outc) {
  int n = blockIdx.x * 256 + threadIdx.x;
  int c = blockIdx.y;
  if (n >= NN) return;
  const float4* f4 = (const float4*)(in + n * 128 + c * 16);
  float4 a = f4[0], b = f4[1], d = f4[2], e = f4[3];
  uint4 o0, o1;
  o0.x = packbf2(a.x, a.y); o0.y = packbf2(a.z, a.w);
  o0.z = packbf2(b.x, b.y); o0.w = packbf2(b.z, b.w);
  o1.x = packbf2(d.x, d.y); o1.y = packbf2(d.z, d.w);
  o1.z = packbf2(e.x, e.y); o1.w = packbf2(e.z, e.w);
  uint4* O = (uint4*)outc;
  O[(c * NN + n) * 2 + 0] = o0;
  O[(c * NN + n) * 2 + 1] = o1;
}

// ---------------- pack weights into MFMA A-operand fragments ----------------
// A-operand = W^T tile: lane holds A[feat=ft*16+(lane&15)][k=ks*32+(lane>>4)*8+j].
// hi/lo split: W = W_hi(bf16) + W_lo(bf16 of residual) keeps f32-level accuracy.

__global__ __launch_bounds__(256) void packW_kernel(const float* __restrict__ W00,
                                                    const float* __restrict__ W01,
                                                    const float* __restrict__ W10,
                                                    const float* __restrict__ W11,
                                                    uint4* __restrict__ Wpack) {
  int t = blockIdx.x * 256 + threadIdx.x;   // 16384 total
  int lane = t & 63;
  int ks   = (t >> 6) & 3;
  int ft   = (t >> 8) & 7;
  int part = (t >> 11) & 1;
  int mat  = (t >> 12) & 1;
  int layer= (t >> 13) & 1;
  const float* Wsrc = layer ? (mat ? W11 : W10) : (mat ? W01 : W00);
  int feat  = ft * 16 + (lane & 15);
  int kbase = ks * 32 + (lane >> 4) * 8;
  uint o[4];
#pragma unroll
  for (int h = 0; h < 4; ++h) {
    float w0 = Wsrc[(kbase + 2 * h) * 128 + feat];
    float w1 = Wsrc[(kbase + 2 * h + 1) * 128 + feat];
    uint h0 = bf16rne(w0), h1 = bf16rne(w1);
    uint v0, v1;
    if (part == 0) { v0 = h0; v1 = h1; }
    else {
      v0 = bf16rne(w0 - __uint_as_float(h0 << 16));
      v1 = bf16rne(w1 - __uint_as_float(h1 << 16));
    }
    o[h] = v0 | (v1 << 16);
  }
  uint4 r; r.x = o[0]; r.y = o[1]; r.z = o[2]; r.w = o[3];
  Wpack[t] = r;
}

// ---------------- CSR build: two-level bucket sort, all writes coalesced --------

__global__ __launch_bounds__(1024) void histA_kernel(const int* __restrict__ dst,
                                                     int* __restrict__ histA) {
  __shared__ int h[NBUCK];
  int tid = threadIdx.x, b = blockIdx.x;
  if (tid < NBUCK) h[tid] = 0;
  __syncthreads();
  const int4* d4 = (const int4*)(dst + b * CPB);
  for (int i = tid; i < CPB / 4; i += 1024) {
    int4 d = d4[i];
    atomicAdd(&h[d.x >> 8], 1);
    atomicAdd(&h[d.y >> 8], 1);
    atomicAdd(&h[d.z >> 8], 1);
    atomicAdd(&h[d.w >> 8], 1);
  }
  __syncthreads();
  if (tid < NBUCK) histA[b * NBUCK + tid] = h[tid];
}

__global__ __launch_bounds__(256) void scanA_kernel(int* __restrict__ histA,
                                                    int* __restrict__ bucket_base) {
  __shared__ int wsum[4];
  int t = threadIdx.x;
  int s = 0;
  if (t < NBUCK) {
#pragma unroll 8
    for (int b = 0; b < NBA; ++b) {
      int v = histA[b * NBUCK + t];
      histA[b * NBUCK + t] = s;
      s += v;
    }
  }
  int lane = t & 63, wid = t >> 6;
  int x = s;
#pragma unroll
  for (int d = 1; d < 64; d <<= 1) {
    int y = __shfl_up(x, d, 64);
    if (lane >= d) x += y;
  }
  if (lane == 63) wsum[wid] = x;
  __syncthreads();
  int woff = 0;
  if (wid > 0) woff += wsum[0];
  if (wid > 1) woff += wsum[1];
  if (wid > 2) woff += wsum[2];
  int excl = woff + x - s;
  if (t < NBUCK) bucket_base[t] = excl;
  if (t == NBUCK - 1) bucket_base[NBUCK] = excl + s;
}

__global__ __launch_bounds__(1024) void scatterA_kernel(const int* __restrict__ src,
                                                        const int* __restrict__ dst,
                                                        const int* __restrict__ histA,
                                                        const int* __restrict__ bucket_base,
                                                        uint* __restrict__ gbuf) {
  __shared__ int cur[NBUCK];
  int tid = threadIdx.x, b = blockIdx.x;
  if (tid < NBUCK) cur[tid] = histA[b * NBUCK + tid] + bucket_base[tid];
  __syncthreads();
  const int4* d4 = (const int4*)(dst + b * CPB);
  const int4* s4 = (const int4*)(src + b * CPB);
  for (int i = tid; i < CPB / 4; i += 1024) {
    int4 d = d4[i];
    int4 s = s4[i];
    int p0 = atomicAdd(&cur[d.x >> 8], 1);
    int p1 = atomicAdd(&cur[d.y >> 8], 1);
    int p2 = atomicAdd(&cur[d.z >> 8], 1);
    int p3 = atomicAdd(&cur[d.w >> 8], 1);
    gbuf[p0] = (uint)s.x | ((uint)(d.x & 255) << 16);
    gbuf[p1] = (uint)s.y | ((uint)(d.y & 255) << 16);
    gbuf[p2] = (uint)s.z | ((uint)(d.z & 255) << 16);
    gbuf[p3] = (uint)s.w | ((uint)(d.w & 255) << 16);
  }
}

__global__ __launch_bounds__(1024) void passB_kernel(const uint* __restrict__ gbuf,
                                                     const int* __restrict__ bucket_base,
                                                     int* __restrict__ offs,
                                                     int* __restrict__ csr) {
  __shared__ int cnt_l[256];
  __shared__ int cur_l[256];
  __shared__ int wsum[4];
  int tid = threadIdx.x, b = blockIdx.x;
  int bbase = bucket_base[b];
  int nE = bucket_base[b + 1] - bbase;
  int lo = b << 8;
  if (tid < 256) cnt_l[tid] = 0;
  __syncthreads();

  const uint* gptr = gbuf + bbase;
  uint pv[MAXBE / 1024];
#pragma unroll
  for (int j = 0; j < MAXBE / 1024; ++j) {
    int i = tid + j * 1024;
    if (i < nE) {
      uint p = gptr[i];
      pv[j] = p;
      atomicAdd(&cnt_l[(p >> 16) & 255], 1);
    }
  }
  __syncthreads();

  int excl = 0, v = 0;
  if (tid < 256) {
    v = cnt_l[tid];
    int lane = tid & 63, wid = tid >> 6;
    int x = v;
#pragma unroll
    for (int d = 1; d < 64; d <<= 1) {
      int y = __shfl_up(x, d, 64);
      if (lane >= d) x += y;
    }
    if (lane == 63) wsum[wid] = x;
    __syncthreads();
    int woff = 0;
    if (wid > 0) woff += wsum[0];
    if (wid > 1) woff += wsum[1];
    if (wid > 2) woff += wsum[2];
    excl = woff + x - v;
    cur_l[tid] = excl;
    int node = lo + tid;
    if (node <= NN) offs[node] = bbase + excl;   // covers offs[0..NN] across buckets
  } else {
    __syncthreads();
  }
  __syncthreads();

#pragma unroll
  for (int j = 0; j < MAXBE / 1024; ++j) {
    int i = tid + j * 1024;
    if (i < nE) {
      uint p = pv[j];
      int r = atomicAdd(&cur_l[(p >> 16) & 255], 1);
      csr[bbase + r] = (int)(p & 0xFFFFu);
    }
  }
}

// ---------------- segment mean, feature-split (chunk-major in/out) ----------------
// 1 thread per node, 16 f32 acc; chunk = bid&7 -> XCD-affine L2-resident plane.
// Block's csr segment staged to LDS (coalesced); 4-neighbor unroll = 8 loads in flight.

__global__ __launch_bounds__(256) void agg_split(const uint* __restrict__ Xc,
                                                 const int* __restrict__ csr,
                                                 const int* __restrict__ offs,
                                                 uint* __restrict__ outc, int N) {
  __shared__ int csr_l[SEGCAP];
  int tid = threadIdx.x;
  int chunk = blockIdx.x & 7;
  int nb = blockIdx.x >> 3;
  int n0 = nb * 256;
  int hi = n0 + 256; if (hi > N) hi = N;
  int segs = offs[n0];
  int sege = offs[hi];
  int len = sege - segs;
  int L = len < SEGCAP ? len : SEGCAP;
  for (int i = tid; i < L; i += 256) csr_l[i] = csr[segs + i];
  __syncthreads();
  int n = n0 + tid;
  if (n >= N) return;
  int s = offs[n], e = offs[n + 1];
  const uint4* __restrict__ Xp = ((const uint4*)Xc) + (size_t)chunk * N * 2;

  float acc[16];
#pragma unroll
  for (int i = 0; i < 16; ++i) acc[i] = 0.f;

  int j = s;
  for (; j + 4 <= e; j += 4) {
    int j0 = j - segs;
    int i0 = (j0 + 0 < L) ? csr_l[j0 + 0] : csr[j + 0];
    int i1 = (j0 + 1 < L) ? csr_l[j0 + 1] : csr[j + 1];
    int i2 = (j0 + 2 < L) ? csr_l[j0 + 2] : csr[j + 2];
    int i3 = (j0 + 3 < L) ? csr_l[j0 + 3] : csr[j + 3];
    uint4 a0 = Xp[i0 * 2], b0 = Xp[i0 * 2 + 1];
    uint4 a1 = Xp[i1 * 2], b1 = Xp[i1 * 2 + 1];
    uint4 a2 = Xp[i2 * 2], b2 = Xp[i2 * 2 + 1];
    uint4 a3 = Xp[i3 * 2], b3 = Xp[i3 * 2 + 1];
    add8(a0, acc); add8(b0, acc + 8);
    add8(a1, acc); add8(b1, acc + 8);
    add8(a2, acc); add8(b2, acc + 8);
    add8(a3, acc); add8(b3, acc + 8);
  }
  for (; j < e; ++j) {
    int j0 = j - segs;
    int i0 = (j0 < L) ? csr_l[j0] : csr[j];
    uint4 a0 = Xp[i0 * 2], b0 = Xp[i0 * 2 + 1];
    add8(a0, acc); add8(b0, acc + 8);
  }

  float inv = 1.0f / fmaxf((float)(e - s), 1.0f);
  uint4 o0, o1;
  o0.x = packbf2(acc[0] * inv, acc[1] * inv);
  o0.y = packbf2(acc[2] * inv, acc[3] * inv);
  o0.z = packbf2(acc[4] * inv, acc[5] * inv);
  o0.w = packbf2(acc[6] * inv, acc[7] * inv);
  o1.x = packbf2(acc[8] * inv, acc[9] * inv);
  o1.y = packbf2(acc[10] * inv, acc[11] * inv);
  o1.z = packbf2(acc[12] * inv, acc[13] * inv);
  o1.w = packbf2(acc[14] * inv, acc[15] * inv);
  uint4* O = ((uint4*)outc) + (size_t)chunk * N * 2;
  O[n * 2 + 0] = o0;
  O[n * 2 + 1] = o1;
}

// ---------------- MFMA dual-GEMM: Out = relu(As*Ws + An*Wn + b) ----------------
// Chunk-major B-operands: fragment uint4 at ((ks*2 + lhi/2)*N + rr)*2 + (lhi&1)
// = base + ks*4N. D layout (m89/m91): col=lane&15 -> node, row=(lane>>4)*4+reg -> feat.
// Output chunk-major: chunk = ft, uint2 at (ft*N + row)*4 + lhi.

#define MFMA16(a, b, c) __builtin_amdgcn_mfma_f32_16x16x32_bf16((a), (b), (c), 0, 0, 0)

__global__ __launch_bounds__(256) void gemm_mfma(
    const uint* __restrict__ As_g, const uint* __restrict__ An_g,
    const uint4* __restrict__ Wp,   // pre-offset per layer
    const float* __restrict__ bias, uint* __restrict__ Out, int N) {
  int tid = threadIdx.x;
  int lane = tid & 63;
  int w = blockIdx.x * 4 + (tid >> 6);
  int ft = w & 7;
  int ng = w >> 3;
  int l15 = lane & 15, lhi = lane >> 4;
  int hb = lhi >> 1, lb = lhi & 1;
  const int S = 4 * NN;   // ks-stride in uint4

  short8 aH[2][4], aL[2][4];
#pragma unroll
  for (int m = 0; m < 2; ++m)
#pragma unroll
    for (int ks = 0; ks < 4; ++ks) {
      aH[m][ks] = as_short8(Wp[(m * 2 + 0) * 2048 + ft * 256 + ks * 64 + lane]);
      aL[m][ks] = as_short8(Wp[(m * 2 + 1) * 2048 + ft * 256 + ks * 64 + lane]);
    }
  int feat0 = ft * 16 + lhi * 4;
  float bv0 = bias[feat0], bv1 = bias[feat0 + 1];
  float bv2 = bias[feat0 + 2], bv3 = bias[feat0 + 3];

  const uint4* __restrict__ Xs = (const uint4*)As_g;
  const uint4* __restrict__ Xn = (const uint4*)An_g;

  for (int t = 0; t < 8; ++t) {
    int row = ng * 128 + t * 16 + l15;
    int rr = row < N ? row : N - 1;
    int base = (hb * NN + rr) * 2 + lb;
    uint4 bs0 = Xs[base], bs1 = Xs[base + S], bs2 = Xs[base + 2 * S], bs3 = Xs[base + 3 * S];
    uint4 bn0 = Xn[base], bn1 = Xn[base + S], bn2 = Xn[base + 2 * S], bn3 = Xn[base + 3 * S];

    f32x4 acc = {0.f, 0.f, 0.f, 0.f};
    short8 b;
    b = as_short8(bs0); acc = MFMA16(aH[0][0], b, acc); acc = MFMA16(aL[0][0], b, acc);
    b = as_short8(bs1); acc = MFMA16(aH[0][1], b, acc); acc = MFMA16(aL[0][1], b, acc);
    b = as_short8(bs2); acc = MFMA16(aH[0][2], b, acc); acc = MFMA16(aL[0][2], b, acc);
    b = as_short8(bs3); acc = MFMA16(aH[0][3], b, acc); acc = MFMA16(aL[0][3], b, acc);
    b = as_short8(bn0); acc = MFMA16(aH[1][0], b, acc); acc = MFMA16(aL[1][0], b, acc);
    b = as_short8(bn1); acc = MFMA16(aH[1][1], b, acc); acc = MFMA16(aL[1][1], b, acc);
    b = as_short8(bn2); acc = MFMA16(aH[1][2], b, acc); acc = MFMA16(aL[1][2], b, acc);
    b = as_short8(bn3); acc = MFMA16(aH[1][3], b, acc); acc = MFMA16(aL[1][3], b, acc);

    float o0 = fmaxf(acc[0] + bv0, 0.f);
    float o1 = fmaxf(acc[1] + bv1, 0.f);
    float o2 = fmaxf(acc[2] + bv2, 0.f);
    float o3 = fmaxf(acc[3] + bv3, 0.f);
    if (row < N) {
      uint2 st;
      st.x = packbf2(o0, o1);
      st.y = packbf2(o2, o3);
      ((uint2*)Out)[((size_t)ft * NN + row) * 4 + lhi] = st;
    }
  }
}

// ---------------- final FC: chunk-major bf16 [N,128] @ f32 [128,47] + b -> f32 ----

__global__ __launch_bounds__(192) void fc_kernel(const uint* __restrict__ Hc,
                                                 const float* __restrict__ Wg,
                                                 const float* __restrict__ bg,
                                                 float* __restrict__ Out, int N) {
  __shared__ float Hs[32 * 128];
  __shared__ float Wsh[128 * 47];
  int tid = threadIdx.x;
  int rowBase = blockIdx.x * 32;
  for (int i = tid; i < 128 * 47; i += 192) Wsh[i] = Wg[i];
  const uint4* __restrict__ H4 = (const uint4*)Hc;
  for (int i = tid; i < 512; i += 192) {
    int r = i >> 4;
    int sl = i & 15;                 // 16B slice: chunk sl>>1, half sl&1
    int c8 = sl << 3;
    int grow = rowBase + r;
    if (grow >= N) grow = N - 1;
    uint4 v = H4[((size_t)(sl >> 1) * NN + grow) * 2 + (sl & 1)];
    Hs[r * 128 + c8 + 0] = bflo(v.x); Hs[r * 128 + c8 + 1] = bfhi(v.x);
    Hs[r * 128 + c8 + 2] = bflo(v.y); Hs[r * 128 + c8 + 3] = bfhi(v.y);
    Hs[r * 128 + c8 + 4] = bflo(v.z); Hs[r * 128 + c8 + 5] = bfhi(v.z);
    Hs[r * 128 + c8 + 6] = bflo(v.w); Hs[r * 128 + c8 + 7] = bfhi(v.w);
  }
  __syncthreads();
  int c = tid % 48;
  int rg = tid / 48;
  float acc[8] = {0.f, 0.f, 0.f, 0.f, 0.f, 0.f, 0.f, 0.f};
  if (c < 47) {
#pragma unroll 4
    for (int k = 0; k < 128; ++k) {
      float wv = Wsh[k * 47 + c];
#pragma unroll
      for (int i = 0; i < 8; ++i)
        acc[i] += Hs[(rg * 8 + i) * 128 + k] * wv;
    }
    float bb = bg[c];
#pragma unroll
    for (int i = 0; i < 8; ++i) {
      int row = rowBase + rg * 8 + i;
      if (row < N) Out[row * 47 + c] = acc[i] + bb;
    }
  }
}

// ---------------- launch ----------------

extern "C" void kernel_launch(void* const* d_in, const int* in_sizes, int n_in,
                              void* d_out, int out_size, void* d_ws, size_t ws_size,
                              hipStream_t stream) {
  const float* feat    = (const float*)d_in[0];
  const int*   src     = (const int*)d_in[1];
  const int*   dst     = (const int*)d_in[2];
  const float* Wself0  = (const float*)d_in[3];
  const float* Wneigh0 = (const float*)d_in[4];
  const float* b0      = (const float*)d_in[5];
  const float* Wself1  = (const float*)d_in[6];
  const float* Wneigh1 = (const float*)d_in[7];
  const float* b1      = (const float*)d_in[8];
  const float* Wfc     = (const float*)d_in[9];
  const float* bfc     = (const float*)d_in[10];
  float* out = (float*)d_out;

  // workspace (bytes); region A hosts gbuf (dead after passB) -> featc (dead
  // after gemm0) -> h2c (written by gemm1). Total ~47 MB.
  char* w = (char*)d_ws;
  int*   offs    = (int*)(w);                 // (N+1) ints      -> 262144
  int*   bbase   = (int*)(w + 262144);        // NBUCK+1 ints    -> 266240
  int*   histA   = (int*)(w + 266240);        // NBA*NBUCK ints  -> 524288
  int*   csr     = (int*)(w + 524288);        // E ints          -> 7340032
  uint4* Wpack   = (uint4*)(w + 7340032);     // 256 KB          -> 7864320
  uint*  gbuf    = (uint*)(w + 7864320);      // E uints (6.4 MB), region A
  uint*  featc   = (uint*)(w + 7864320);      // 12.8 MB chunk-major, region A
  uint*  h2c     = (uint*)(w + 7864320);      // region A (after featc dead)
  uint*  hnc     = (uint*)(w + 20971520);     // 12.8 MB chunk-major
  uint*  h0c     = (uint*)(w + 34078720);     // 12.8 MB chunk-major -> 47185920

  const int N = NN;

  histA_kernel<<<NBA, 1024, 0, stream>>>(dst, histA);
  scanA_kernel<<<1, 256, 0, stream>>>(histA, bbase);
  scatterA_kernel<<<NBA, 1024, 0, stream>>>(src, dst, histA, bbase, gbuf);
  passB_kernel<<<NBUCK, 1024, 0, stream>>>(gbuf, bbase, offs, csr);

  dim3 tgrid((N + 255) / 256, 8);
  tobf16c_kernel<<<tgrid, 256, 0, stream>>>(feat, featc);
  packW_kernel<<<64, 256, 0, stream>>>(Wself0, Wneigh0, Wself1, Wneigh1, Wpack);

  const int ablocks = 8 * ((N + 255) / 256);         // chunk = bid & 7
  const int gwaves = 8 * ((N + 127) / 128);          // 8 feat-tiles x node-groups
  const int gblocks_mfma = (gwaves + 3) / 4;         // 4 waves/block

  agg_split<<<ablocks, 256, 0, stream>>>(featc, csr, offs, hnc, N);
  gemm_mfma<<<gblocks_mfma, 256, 0, stream>>>(featc, hnc, Wpack, b0, h0c, N);
  agg_split<<<ablocks, 256, 0, stream>>>(h0c, csr, offs, hnc, N);
  gemm_mfma<<<gblocks_mfma, 256, 0, stream>>>(h0c, hnc, Wpack + 8192, b1, h2c, N);
  fc_kernel<<<(N + 31) / 32, 192, 0, stream>>>(h2c, Wfc, bfc, out, N);
}

// Round 10
// 251.386 us; speedup vs baseline: 1.0103x; 1.0103x over previous
//
#include <hip/hip_runtime.h>

#define NN 50000
#define NE 1600000
#define NBA 128          // pass-A edge chunks (blocks)
#define CPB (NE / NBA)   // 12500 edges per chunk
#define NBUCK 196        // dst>>8 buckets (256 nodes each); 49999>>8 = 195
#define MAXBE 12288      // per-bucket edge cap: mean 8192, sigma~90 -> +45 sigma

typedef unsigned int uint;
typedef __attribute__((ext_vector_type(8))) short short8;   // 8 bf16 (4 VGPRs)
typedef __attribute__((ext_vector_type(4))) float f32x4;    // MFMA accumulator

// ---------------- bf16 helpers (packed pairs in uint32) ----------------

__device__ __forceinline__ uint bf16rne(float f) {
  uint u = __float_as_uint(f);
  return (u + 0x7fffu + ((u >> 16) & 1u)) >> 16;
}
__device__ __forceinline__ uint packbf2(float lo, float hi) {
  return bf16rne(lo) | (bf16rne(hi) << 16);
}
__device__ __forceinline__ float bflo(uint u) { return __uint_as_float(u << 16); }
__device__ __forceinline__ float bfhi(uint u) { return __uint_as_float(u & 0xffff0000u); }

__device__ __forceinline__ short8 as_short8(uint4 v) {
  union { uint4 u; short8 s; } cv; cv.u = v; return cv.s;
}

__device__ __forceinline__ void add8(const uint4 v, float* a) {
  a[0] += bflo(v.x); a[1] += bfhi(v.x);
  a[2] += bflo(v.y); a[3] += bfhi(v.y);
  a[4] += bflo(v.z); a[5] += bfhi(v.z);
  a[6] += bflo(v.w); a[7] += bfhi(v.w);
}

// f32 [n8*8] -> packed bf16 [n8 uint4]
__global__ __launch_bounds__(256) void tobf16_kernel(const float* __restrict__ in,
                                                     uint* __restrict__ outb, int n8) {
  int t = blockIdx.x * 256 + threadIdx.x;
  if (t < n8) {
    float4 a = ((const float4*)in)[2 * t];
    float4 b = ((const float4*)in)[2 * t + 1];
    uint4 o;
    o.x = packbf2(a.x, a.y);
    o.y = packbf2(a.z, a.w);
    o.z = packbf2(b.x, b.y);
    o.w = packbf2(b.z, b.w);
    ((uint4*)outb)[t] = o;
  }
}

// ---------------- pack weights into MFMA A-operand fragments ----------------
// A-operand = W^T tile: lane holds A[feat=ft*16+(lane&15)][k=ks*32+(lane>>4)*8+j].
// hi/lo split: W = W_hi(bf16) + W_lo(bf16 of residual) keeps f32-level accuracy.

__global__ __launch_bounds__(256) void packW_kernel(const float* __restrict__ W00,
                                                    const float* __restrict__ W01,
                                                    const float* __restrict__ W10,
                                                    const float* __restrict__ W11,
                                                    uint4* __restrict__ Wpack) {
  int t = blockIdx.x * 256 + threadIdx.x;   // 16384 total
  int lane = t & 63;
  int ks   = (t >> 6) & 3;
  int ft   = (t >> 8) & 7;
  int part = (t >> 11) & 1;
  int mat  = (t >> 12) & 1;
  int layer= (t >> 13) & 1;
  const float* Wsrc = layer ? (mat ? W11 : W10) : (mat ? W01 : W00);
  int feat  = ft * 16 + (lane & 15);
  int kbase = ks * 32 + (lane >> 4) * 8;
  uint o[4];
#pragma unroll
  for (int h = 0; h < 4; ++h) {
    float w0 = Wsrc[(kbase + 2 * h) * 128 + feat];
    float w1 = Wsrc[(kbase + 2 * h + 1) * 128 + feat];
    uint h0 = bf16rne(w0), h1 = bf16rne(w1);
    uint v0, v1;
    if (part == 0) { v0 = h0; v1 = h1; }
    else {
      v0 = bf16rne(w0 - __uint_as_float(h0 << 16));
      v1 = bf16rne(w1 - __uint_as_float(h1 << 16));
    }
    o[h] = v0 | (v1 << 16);
  }
  uint4 r; r.x = o[0]; r.y = o[1]; r.z = o[2]; r.w = o[3];
  Wpack[t] = r;
}

// ---------------- CSR build: two-level bucket sort, all writes coalesced --------
// bucket(d) = d >> 8 (256 nodes / bucket, NBUCK=196).

__global__ __launch_bounds__(1024) void histA_kernel(const int* __restrict__ dst,
                                                     int* __restrict__ histA) {
  __shared__ int h[NBUCK];
  int tid = threadIdx.x, b = blockIdx.x;
  if (tid < NBUCK) h[tid] = 0;
  __syncthreads();
  const int4* d4 = (const int4*)(dst + b * CPB);
  for (int i = tid; i < CPB / 4; i += 1024) {
    int4 d = d4[i];
    atomicAdd(&h[d.x >> 8], 1);
    atomicAdd(&h[d.y >> 8], 1);
    atomicAdd(&h[d.z >> 8], 1);
    atomicAdd(&h[d.w >> 8], 1);
  }
  __syncthreads();
  if (tid < NBUCK) histA[b * NBUCK + tid] = h[tid];
}

__global__ __launch_bounds__(256) void scanA_kernel(int* __restrict__ histA,
                                                    int* __restrict__ bucket_base) {
  __shared__ int wsum[4];
  int t = threadIdx.x;
  int s = 0;
  if (t < NBUCK) {
#pragma unroll 8
    for (int b = 0; b < NBA; ++b) {
      int v = histA[b * NBUCK + t];
      histA[b * NBUCK + t] = s;
      s += v;
    }
  }
  int lane = t & 63, wid = t >> 6;
  int x = s;
#pragma unroll
  for (int d = 1; d < 64; d <<= 1) {
    int y = __shfl_up(x, d, 64);
    if (lane >= d) x += y;
  }
  if (lane == 63) wsum[wid] = x;
  __syncthreads();
  int woff = 0;
  if (wid > 0) woff += wsum[0];
  if (wid > 1) woff += wsum[1];
  if (wid > 2) woff += wsum[2];
  int excl = woff + x - s;
  if (t < NBUCK) bucket_base[t] = excl;
  if (t == NBUCK - 1) bucket_base[NBUCK] = excl + s;
}

__global__ __launch_bounds__(1024) void scatterA_kernel(const int* __restrict__ src,
                                                        const int* __restrict__ dst,
                                                        const int* __restrict__ histA,
                                                        const int* __restrict__ bucket_base,
                                                        uint* __restrict__ gbuf) {
  __shared__ int cur[NBUCK];
  int tid = threadIdx.x, b = blockIdx.x;
  if (tid < NBUCK) cur[tid] = histA[b * NBUCK + tid] + bucket_base[tid];
  __syncthreads();
  const int4* d4 = (const int4*)(dst + b * CPB);
  const int4* s4 = (const int4*)(src + b * CPB);
  for (int i = tid; i < CPB / 4; i += 1024) {
    int4 d = d4[i];
    int4 s = s4[i];
    int p0 = atomicAdd(&cur[d.x >> 8], 1);
    int p1 = atomicAdd(&cur[d.y >> 8], 1);
    int p2 = atomicAdd(&cur[d.z >> 8], 1);
    int p3 = atomicAdd(&cur[d.w >> 8], 1);
    gbuf[p0] = (uint)s.x | ((uint)(d.x & 255) << 16);
    gbuf[p1] = (uint)s.y | ((uint)(d.y & 255) << 16);
    gbuf[p2] = (uint)s.z | ((uint)(d.z & 255) << 16);
    gbuf[p3] = (uint)s.w | ((uint)(d.w & 255) << 16);
  }
}

__global__ __launch_bounds__(1024) void passB_kernel(const uint* __restrict__ gbuf,
                                                     const int* __restrict__ bucket_base,
                                                     int* __restrict__ offs,
                                                     int* __restrict__ csr) {
  __shared__ int cnt_l[256];
  __shared__ int cur_l[256];
  __shared__ int wsum[4];
  int tid = threadIdx.x, b = blockIdx.x;
  int bbase = bucket_base[b];
  int nE = bucket_base[b + 1] - bbase;
  int lo = b << 8;
  if (tid < 256) cnt_l[tid] = 0;
  __syncthreads();

  const uint* gptr = gbuf + bbase;
  uint pv[MAXBE / 1024];
#pragma unroll
  for (int j = 0; j < MAXBE / 1024; ++j) {
    int i = tid + j * 1024;
    if (i < nE) {
      uint p = gptr[i];
      pv[j] = p;
      atomicAdd(&cnt_l[(p >> 16) & 255], 1);
    }
  }
  __syncthreads();

  int excl = 0, v = 0;
  if (tid < 256) {
    v = cnt_l[tid];
    int lane = tid & 63, wid = tid >> 6;
    int x = v;
#pragma unroll
    for (int d = 1; d < 64; d <<= 1) {
      int y = __shfl_up(x, d, 64);
      if (lane >= d) x += y;
    }
    if (lane == 63) wsum[wid] = x;
    __syncthreads();
    int woff = 0;
    if (wid > 0) woff += wsum[0];
    if (wid > 1) woff += wsum[1];
    if (wid > 2) woff += wsum[2];
    excl = woff + x - v;
    cur_l[tid] = excl;
    int node = lo + tid;
    if (node <= NN) offs[node] = bbase + excl;   // covers offs[0..NN] across buckets
  } else {
    __syncthreads();
  }
  __syncthreads();

#pragma unroll
  for (int j = 0; j < MAXBE / 1024; ++j) {
    int i = tid + j * 1024;
    if (i < nE) {
      uint p = pv[j];
      int r = atomicAdd(&cur_l[(p >> 16) & 255], 1);
      csr[bbase + r] = (int)(p & 0xFFFFu);
    }
  }
}

// ---------------- segment mean over packed-bf16 rows ----------------
// 256 threads = 16 nodes/block; 16 lanes per node, uint4 = 8 dims per lane.
// 16-deep neighbor unroll: 16 independent uint4 gathers in flight per lane
// (round-8 had 8; agg is latency/MLP-bound, not byte-bound).

__global__ __launch_bounds__(256) void agg_kernel(const uint* __restrict__ Xb,
                                                  const int* __restrict__ csr,
                                                  const int* __restrict__ offs,
                                                  uint* __restrict__ outb, int N) {
  const uint4* __restrict__ X4 = (const uint4*)Xb;  // 16 uint4 per 128-dim row
  int tid = threadIdx.x;
  int slot = tid >> 4;
  int lane = tid & 15;
  int n = blockIdx.x * 16 + slot;
  if (n >= N) return;
  int s = offs[n], e = offs[n + 1];

  float aA[8] = {0.f, 0.f, 0.f, 0.f, 0.f, 0.f, 0.f, 0.f};
  float aB[8] = {0.f, 0.f, 0.f, 0.f, 0.f, 0.f, 0.f, 0.f};

  int j = s;
  for (; j + 16 <= e; j += 16) {
    int idx[16];
#pragma unroll
    for (int q = 0; q < 16; ++q) idx[q] = csr[j + q];
    uint4 v[16];
#pragma unroll
    for (int q = 0; q < 16; ++q) v[q] = X4[idx[q] * 16 + lane];
#pragma unroll
    for (int q = 0; q < 16; q += 2) { add8(v[q], aA); add8(v[q + 1], aB); }
  }
  for (; j + 4 <= e; j += 4) {
    int i0 = csr[j + 0], i1 = csr[j + 1], i2 = csr[j + 2], i3 = csr[j + 3];
    uint4 v0 = X4[i0 * 16 + lane];
    uint4 v1 = X4[i1 * 16 + lane];
    uint4 v2 = X4[i2 * 16 + lane];
    uint4 v3 = X4[i3 * 16 + lane];
    add8(v0, aA); add8(v1, aB); add8(v2, aA); add8(v3, aB);
  }
  for (; j < e; ++j) {
    uint4 v = X4[csr[j] * 16 + lane];
    add8(v, aA);
  }

  float inv = 1.0f / fmaxf((float)(e - s), 1.0f);
  uint4 o;
  o.x = packbf2((aA[0] + aB[0]) * inv, (aA[1] + aB[1]) * inv);
  o.y = packbf2((aA[2] + aB[2]) * inv, (aA[3] + aB[3]) * inv);
  o.z = packbf2((aA[4] + aB[4]) * inv, (aA[5] + aB[5]) * inv);
  o.w = packbf2((aA[6] + aB[6]) * inv, (aA[7] + aB[7]) * inv);
  ((uint4*)outb)[n * 16 + lane] = o;
}

// ---------------- MFMA dual-GEMM: Out = relu(As*Ws + An*Wn + b) ----------------
// D layout (m89/m91-verified): col=lane&15 -> node, row=(lane>>4)*4+reg -> feat.

#define MFMA16(a, b, c) __builtin_amdgcn_mfma_f32_16x16x32_bf16((a), (b), (c), 0, 0, 0)

__global__ __launch_bounds__(256) void gemm_mfma(
    const uint* __restrict__ As_g, const uint* __restrict__ An_g,
    const uint4* __restrict__ Wp,   // pre-offset per layer
    const float* __restrict__ bias, uint* __restrict__ Out, int N) {
  int tid = threadIdx.x;
  int lane = tid & 63;
  int w = blockIdx.x * 4 + (tid >> 6);
  int ft = w & 7;
  int ng = w >> 3;
  int l15 = lane & 15, lhi = lane >> 4;

  short8 aH[2][4], aL[2][4];
#pragma unroll
  for (int m = 0; m < 2; ++m)
#pragma unroll
    for (int ks = 0; ks < 4; ++ks) {
      aH[m][ks] = as_short8(Wp[(m * 2 + 0) * 2048 + ft * 256 + ks * 64 + lane]);
      aL[m][ks] = as_short8(Wp[(m * 2 + 1) * 2048 + ft * 256 + ks * 64 + lane]);
    }
  int feat0 = ft * 16 + lhi * 4;
  float bv0 = bias[feat0], bv1 = bias[feat0 + 1];
  float bv2 = bias[feat0 + 2], bv3 = bias[feat0 + 3];

  const uint4* __restrict__ Xs = (const uint4*)As_g;
  const uint4* __restrict__ Xn = (const uint4*)An_g;

  for (int t = 0; t < 8; ++t) {
    int row = ng * 128 + t * 16 + l15;
    int rr = row < N ? row : N - 1;
    const uint4* ps = Xs + rr * 16 + lhi;
    const uint4* pn = Xn + rr * 16 + lhi;
    uint4 bs0 = ps[0], bs1 = ps[4], bs2 = ps[8], bs3 = ps[12];
    uint4 bn0 = pn[0], bn1 = pn[4], bn2 = pn[8], bn3 = pn[12];

    f32x4 acc = {0.f, 0.f, 0.f, 0.f};
    short8 b;
    b = as_short8(bs0); acc = MFMA16(aH[0][0], b, acc); acc = MFMA16(aL[0][0], b, acc);
    b = as_short8(bs1); acc = MFMA16(aH[0][1], b, acc); acc = MFMA16(aL[0][1], b, acc);
    b = as_short8(bs2); acc = MFMA16(aH[0][2], b, acc); acc = MFMA16(aL[0][2], b, acc);
    b = as_short8(bs3); acc = MFMA16(aH[0][3], b, acc); acc = MFMA16(aL[0][3], b, acc);
    b = as_short8(bn0); acc = MFMA16(aH[1][0], b, acc); acc = MFMA16(aL[1][0], b, acc);
    b = as_short8(bn1); acc = MFMA16(aH[1][1], b, acc); acc = MFMA16(aL[1][1], b, acc);
    b = as_short8(bn2); acc = MFMA16(aH[1][2], b, acc); acc = MFMA16(aL[1][2], b, acc);
    b = as_short8(bn3); acc = MFMA16(aH[1][3], b, acc); acc = MFMA16(aL[1][3], b, acc);

    float o0 = fmaxf(acc[0] + bv0, 0.f);
    float o1 = fmaxf(acc[1] + bv1, 0.f);
    float o2 = fmaxf(acc[2] + bv2, 0.f);
    float o3 = fmaxf(acc[3] + bv3, 0.f);
    if (row < N) {
      uint2 st;
      st.x = packbf2(o0, o1);
      st.y = packbf2(o2, o3);
      ((uint2*)Out)[row * 32 + ft * 4 + lhi] = st;
    }
  }
}

// ---------------- final FC: bf16 [N,128] @ f32 [128,47] + b -> f32 out ----------

__global__ __launch_bounds__(192) void fc_kernel(const uint* __restrict__ Hb,
                                                 const float* __restrict__ Wg,
                                                 const float* __restrict__ bg,
                                                 float* __restrict__ Out, int N) {
  __shared__ float Hs[32 * 128];
  __shared__ float Wsh[128 * 47];
  int tid = threadIdx.x;
  int rowBase = blockIdx.x * 32;
  for (int i = tid; i < 128 * 47; i += 192) Wsh[i] = Wg[i];
  const uint4* __restrict__ H4 = (const uint4*)Hb;
  for (int i = tid; i < 512; i += 192) {
    int r = i >> 4;
    int c8 = (i & 15) << 3;
    int grow = rowBase + r;
    if (grow >= N) grow = N - 1;
    uint4 v = H4[grow * 16 + (i & 15)];
    Hs[r * 128 + c8 + 0] = bflo(v.x); Hs[r * 128 + c8 + 1] = bfhi(v.x);
    Hs[r * 128 + c8 + 2] = bflo(v.y); Hs[r * 128 + c8 + 3] = bfhi(v.y);
    Hs[r * 128 + c8 + 4] = bflo(v.z); Hs[r * 128 + c8 + 5] = bfhi(v.z);
    Hs[r * 128 + c8 + 6] = bflo(v.w); Hs[r * 128 + c8 + 7] = bfhi(v.w);
  }
  __syncthreads();
  int c = tid % 48;
  int rg = tid / 48;
  float acc[8] = {0.f, 0.f, 0.f, 0.f, 0.f, 0.f, 0.f, 0.f};
  if (c < 47) {
#pragma unroll 4
    for (int k = 0; k < 128; ++k) {
      float wv = Wsh[k * 47 + c];
#pragma unroll
      for (int i = 0; i < 8; ++i)
        acc[i] += Hs[(rg * 8 + i) * 128 + k] * wv;
    }
    float bb = bg[c];
#pragma unroll
    for (int i = 0; i < 8; ++i) {
      int row = rowBase + rg * 8 + i;
      if (row < N) Out[row * 47 + c] = acc[i] + bb;
    }
  }
}

// ---------------- launch ----------------

extern "C" void kernel_launch(void* const* d_in, const int* in_sizes, int n_in,
                              void* d_out, int out_size, void* d_ws, size_t ws_size,
                              hipStream_t stream) {
  const float* feat    = (const float*)d_in[0];
  const int*   src     = (const int*)d_in[1];
  const int*   dst     = (const int*)d_in[2];
  const float* Wself0  = (const float*)d_in[3];
  const float* Wneigh0 = (const float*)d_in[4];
  const float* b0      = (const float*)d_in[5];
  const float* Wself1  = (const float*)d_in[6];
  const float* Wneigh1 = (const float*)d_in[7];
  const float* b1      = (const float*)d_in[8];
  const float* Wfc     = (const float*)d_in[9];
  const float* bfc     = (const float*)d_in[10];
  float* out = (float*)d_out;

  // workspace (bytes); overlaps exploit liveness:
  //   gbuf dead after passB; featb dead after gemm0 -> h2b reuses featb's slot.
  char* w = (char*)d_ws;
  int*   offs    = (int*)(w);                 // (N+1) ints
  int*   bbase   = (int*)(w + 262144);        // NBUCK+1 ints
  int*   histA   = (int*)(w + 266240);        // NBA*NBUCK ints (~100 KB)
  int*   csr     = (int*)(w + 524288);        // E ints -> ends 6,924,288
  uint4* Wpack   = (uint4*)(w + 7340032);     // 16384 uint4 = 256 KB
  uint*  featb   = (uint*)(w + 7864320);      // N*64 uints (bf16)
  uint*  h2b     = (uint*)(w + 7864320);      // same region, after featb dead
  uint*  gbuf    = (uint*)(w + 20971520);     // E uints = 6.4 MB, dead after passB
  uint*  hnb     = (uint*)(w + 27787264);     // N*64 uints (bf16)
  uint*  h0b     = (uint*)(w + 41943040);     // N*64 uints (bf16)

  const int N = NN;

  histA_kernel<<<NBA, 1024, 0, stream>>>(dst, histA);
  scanA_kernel<<<1, 256, 0, stream>>>(histA, bbase);
  scatterA_kernel<<<NBA, 1024, 0, stream>>>(src, dst, histA, bbase, gbuf);
  passB_kernel<<<NBUCK, 1024, 0, stream>>>(gbuf, bbase, offs, csr);

  tobf16_kernel<<<(N * 16 + 255) / 256, 256, 0, stream>>>(feat, featb, N * 16);
  packW_kernel<<<64, 256, 0, stream>>>(Wself0, Wneigh0, Wself1, Wneigh1, Wpack);

  const int gwaves = 8 * ((N + 127) / 128);          // 8 feat-tiles x node-groups
  const int gblocks_mfma = (gwaves + 3) / 4;         // 4 waves/block

  agg_kernel<<<(N + 15) / 16, 256, 0, stream>>>(featb, csr, offs, hnb, N);
  gemm_mfma<<<gblocks_mfma, 256, 0, stream>>>(featb, hnb, Wpack, b0, h0b, N);
  agg_kernel<<<(N + 15) / 16, 256, 0, stream>>>(h0b, csr, offs, hnb, N);
  gemm_mfma<<<gblocks_mfma, 256, 0, stream>>>(h0b, hnb, Wpack + 8192, b1, h2b, N);
  fc_kernel<<<(N + 31) / 32, 192, 0, stream>>>(h2b, Wfc, bfc, out, N);
}

// Round 11
// 227.709 us; speedup vs baseline: 1.1154x; 1.1040x over previous
//
#include <hip/hip_runtime.h>

#define NN 50000
#define NE 1600000
#define NBA 128          // pass-A edge chunks (blocks)
#define CPB (NE / NBA)   // 12500 edges per chunk
#define NBUCK 196        // dst>>8 buckets (256 nodes each); 49999>>8 = 195
#define MAXBE 12288      // per-bucket edge cap: mean 8192, sigma~90 -> +45 sigma

typedef unsigned int uint;
typedef __attribute__((ext_vector_type(8))) short short8;   // 8 bf16 (4 VGPRs)
typedef __attribute__((ext_vector_type(4))) float f32x4;    // MFMA accumulator
typedef __attribute__((ext_vector_type(4), aligned(4))) float f32x4u;  // 4B-aligned store

// ---------------- bf16 helpers (packed pairs in uint32) ----------------

__device__ __forceinline__ uint bf16rne(float f) {
  uint u = __float_as_uint(f);
  return (u + 0x7fffu + ((u >> 16) & 1u)) >> 16;
}
__device__ __forceinline__ uint packbf2(float lo, float hi) {
  return bf16rne(lo) | (bf16rne(hi) << 16);
}
__device__ __forceinline__ float bflo(uint u) { return __uint_as_float(u << 16); }
__device__ __forceinline__ float bfhi(uint u) { return __uint_as_float(u & 0xffff0000u); }

__device__ __forceinline__ short8 as_short8(uint4 v) {
  union { uint4 u; short8 s; } cv; cv.u = v; return cv.s;
}

__device__ __forceinline__ void add8(const uint4 v, float* a) {
  a[0] += bflo(v.x); a[1] += bfhi(v.x);
  a[2] += bflo(v.y); a[3] += bfhi(v.y);
  a[4] += bflo(v.z); a[5] += bfhi(v.z);
  a[6] += bflo(v.w); a[7] += bfhi(v.w);
}

// f32 [n8*8] -> packed bf16 [n8 uint4]
__global__ __launch_bounds__(256) void tobf16_kernel(const float* __restrict__ in,
                                                     uint* __restrict__ outb, int n8) {
  int t = blockIdx.x * 256 + threadIdx.x;
  if (t < n8) {
    float4 a = ((const float4*)in)[2 * t];
    float4 b = ((const float4*)in)[2 * t + 1];
    uint4 o;
    o.x = packbf2(a.x, a.y);
    o.y = packbf2(a.z, a.w);
    o.z = packbf2(b.x, b.y);
    o.w = packbf2(b.z, b.w);
    ((uint4*)outb)[t] = o;
  }
}

// ---------------- pack weights into MFMA A-operand fragments ----------------
// A-operand = W^T tile: lane holds A[feat=ft*16+(lane&15)][k=ks*32+(lane>>4)*8+j].
// hi/lo split: W = W_hi(bf16) + W_lo(bf16 of residual) keeps f32-level accuracy.
// t < 16384: layer weights (layout as before). t in [16384,17920): Wfc
// fragments, index ((part*3+ct)*4+ks)*64+lane, cols padded 47->48.

__global__ __launch_bounds__(256) void packW_kernel(const float* __restrict__ W00,
                                                    const float* __restrict__ W01,
                                                    const float* __restrict__ W10,
                                                    const float* __restrict__ W11,
                                                    const float* __restrict__ Wfc,
                                                    uint4* __restrict__ Wpack) {
  int t = blockIdx.x * 256 + threadIdx.x;
  if (t < 16384) {
    int lane = t & 63;
    int ks   = (t >> 6) & 3;
    int ft   = (t >> 8) & 7;
    int part = (t >> 11) & 1;
    int mat  = (t >> 12) & 1;
    int layer= (t >> 13) & 1;
    const float* Wsrc = layer ? (mat ? W11 : W10) : (mat ? W01 : W00);
    int feat  = ft * 16 + (lane & 15);
    int kbase = ks * 32 + (lane >> 4) * 8;
    uint o[4];
#pragma unroll
    for (int h = 0; h < 4; ++h) {
      float w0 = Wsrc[(kbase + 2 * h) * 128 + feat];
      float w1 = Wsrc[(kbase + 2 * h + 1) * 128 + feat];
      uint h0 = bf16rne(w0), h1 = bf16rne(w1);
      uint v0, v1;
      if (part == 0) { v0 = h0; v1 = h1; }
      else {
        v0 = bf16rne(w0 - __uint_as_float(h0 << 16));
        v1 = bf16rne(w1 - __uint_as_float(h1 << 16));
      }
      o[h] = v0 | (v1 << 16);
    }
    uint4 r; r.x = o[0]; r.y = o[1]; r.z = o[2]; r.w = o[3];
    Wpack[t] = r;
  } else if (t < 16384 + 1536) {
    int tt = t - 16384;
    int lane = tt & 63;
    int ks   = (tt >> 6) & 3;
    int ct   = (tt >> 8) % 3;
    int part = tt / 768;
    int col  = ct * 16 + (lane & 15);
    int kbase = ks * 32 + (lane >> 4) * 8;
    uint o[4];
#pragma unroll
    for (int h = 0; h < 4; ++h) {
      float w0 = (col < 47) ? Wfc[(kbase + 2 * h) * 47 + col] : 0.f;
      float w1 = (col < 47) ? Wfc[(kbase + 2 * h + 1) * 47 + col] : 0.f;
      uint h0 = bf16rne(w0), h1 = bf16rne(w1);
      uint v0, v1;
      if (part == 0) { v0 = h0; v1 = h1; }
      else {
        v0 = bf16rne(w0 - __uint_as_float(h0 << 16));
        v1 = bf16rne(w1 - __uint_as_float(h1 << 16));
      }
      o[h] = v0 | (v1 << 16);
    }
    uint4 r; r.x = o[0]; r.y = o[1]; r.z = o[2]; r.w = o[3];
    Wpack[t] = r;
  }
}

// ---------------- CSR build: two-level bucket sort, all writes coalesced --------
// bucket(d) = d >> 8 (256 nodes / bucket, NBUCK=196).

__global__ __launch_bounds__(1024) void histA_kernel(const int* __restrict__ dst,
                                                     int* __restrict__ histA) {
  __shared__ int h[NBUCK];
  int tid = threadIdx.x, b = blockIdx.x;
  if (tid < NBUCK) h[tid] = 0;
  __syncthreads();
  const int4* d4 = (const int4*)(dst + b * CPB);
  for (int i = tid; i < CPB / 4; i += 1024) {
    int4 d = d4[i];
    atomicAdd(&h[d.x >> 8], 1);
    atomicAdd(&h[d.y >> 8], 1);
    atomicAdd(&h[d.z >> 8], 1);
    atomicAdd(&h[d.w >> 8], 1);
  }
  __syncthreads();
  if (tid < NBUCK) histA[b * NBUCK + tid] = h[tid];
}

__global__ __launch_bounds__(256) void scanA_kernel(int* __restrict__ histA,
                                                    int* __restrict__ bucket_base) {
  __shared__ int wsum[4];
  int t = threadIdx.x;
  int s = 0;
  if (t < NBUCK) {
#pragma unroll 8
    for (int b = 0; b < NBA; ++b) {
      int v = histA[b * NBUCK + t];
      histA[b * NBUCK + t] = s;
      s += v;
    }
  }
  int lane = t & 63, wid = t >> 6;
  int x = s;
#pragma unroll
  for (int d = 1; d < 64; d <<= 1) {
    int y = __shfl_up(x, d, 64);
    if (lane >= d) x += y;
  }
  if (lane == 63) wsum[wid] = x;
  __syncthreads();
  int woff = 0;
  if (wid > 0) woff += wsum[0];
  if (wid > 1) woff += wsum[1];
  if (wid > 2) woff += wsum[2];
  int excl = woff + x - s;
  if (t < NBUCK) bucket_base[t] = excl;
  if (t == NBUCK - 1) bucket_base[NBUCK] = excl + s;
}

__global__ __launch_bounds__(1024) void scatterA_kernel(const int* __restrict__ src,
                                                        const int* __restrict__ dst,
                                                        const int* __restrict__ histA,
                                                        const int* __restrict__ bucket_base,
                                                        uint* __restrict__ gbuf) {
  __shared__ int cur[NBUCK];
  int tid = threadIdx.x, b = blockIdx.x;
  if (tid < NBUCK) cur[tid] = histA[b * NBUCK + tid] + bucket_base[tid];
  __syncthreads();
  const int4* d4 = (const int4*)(dst + b * CPB);
  const int4* s4 = (const int4*)(src + b * CPB);
  for (int i = tid; i < CPB / 4; i += 1024) {
    int4 d = d4[i];
    int4 s = s4[i];
    int p0 = atomicAdd(&cur[d.x >> 8], 1);
    int p1 = atomicAdd(&cur[d.y >> 8], 1);
    int p2 = atomicAdd(&cur[d.z >> 8], 1);
    int p3 = atomicAdd(&cur[d.w >> 8], 1);
    gbuf[p0] = (uint)s.x | ((uint)(d.x & 255) << 16);
    gbuf[p1] = (uint)s.y | ((uint)(d.y & 255) << 16);
    gbuf[p2] = (uint)s.z | ((uint)(d.z & 255) << 16);
    gbuf[p3] = (uint)s.w | ((uint)(d.w & 255) << 16);
  }
}

__global__ __launch_bounds__(1024) void passB_kernel(const uint* __restrict__ gbuf,
                                                     const int* __restrict__ bucket_base,
                                                     int* __restrict__ offs,
                                                     int* __restrict__ csr) {
  __shared__ int cnt_l[256];
  __shared__ int cur_l[256];
  __shared__ int wsum[4];
  int tid = threadIdx.x, b = blockIdx.x;
  int bbase = bucket_base[b];
  int nE = bucket_base[b + 1] - bbase;
  int lo = b << 8;
  if (tid < 256) cnt_l[tid] = 0;
  __syncthreads();

  const uint* gptr = gbuf + bbase;
  uint pv[MAXBE / 1024];
#pragma unroll
  for (int j = 0; j < MAXBE / 1024; ++j) {
    int i = tid + j * 1024;
    if (i < nE) {
      uint p = gptr[i];
      pv[j] = p;
      atomicAdd(&cnt_l[(p >> 16) & 255], 1);
    }
  }
  __syncthreads();

  int excl = 0, v = 0;
  if (tid < 256) {
    v = cnt_l[tid];
    int lane = tid & 63, wid = tid >> 6;
    int x = v;
#pragma unroll
    for (int d = 1; d < 64; d <<= 1) {
      int y = __shfl_up(x, d, 64);
      if (lane >= d) x += y;
    }
    if (lane == 63) wsum[wid] = x;
    __syncthreads();
    int woff = 0;
    if (wid > 0) woff += wsum[0];
    if (wid > 1) woff += wsum[1];
    if (wid > 2) woff += wsum[2];
    excl = woff + x - v;
    cur_l[tid] = excl;
    int node = lo + tid;
    if (node <= NN) offs[node] = bbase + excl;   // covers offs[0..NN] across buckets
  } else {
    __syncthreads();
  }
  __syncthreads();

#pragma unroll
  for (int j = 0; j < MAXBE / 1024; ++j) {
    int i = tid + j * 1024;
    if (i < nE) {
      uint p = pv[j];
      int r = atomicAdd(&cur_l[(p >> 16) & 255], 1);
      csr[bbase + r] = (int)(p & 0xFFFFu);
    }
  }
}

// ---------------- segment mean over packed-bf16 rows (round-8 proven form) -------
// 256 threads = 16 nodes/block; 16 lanes per node, uint4 = 8 dims per lane.

__global__ __launch_bounds__(256) void agg_kernel(const uint* __restrict__ Xb,
                                                  const int* __restrict__ csr,
                                                  const int* __restrict__ offs,
                                                  uint* __restrict__ outb, int N) {
  const uint4* __restrict__ X4 = (const uint4*)Xb;  // 16 uint4 per 128-dim row
  int tid = threadIdx.x;
  int slot = tid >> 4;
  int lane = tid & 15;
  int n = blockIdx.x * 16 + slot;
  if (n >= N) return;
  int s = offs[n], e = offs[n + 1];

  float aA[8] = {0.f, 0.f, 0.f, 0.f, 0.f, 0.f, 0.f, 0.f};
  float aB[8] = {0.f, 0.f, 0.f, 0.f, 0.f, 0.f, 0.f, 0.f};

  int j = s;
  for (; j + 8 <= e; j += 8) {
    int i0 = csr[j + 0], i1 = csr[j + 1], i2 = csr[j + 2], i3 = csr[j + 3];
    int i4 = csr[j + 4], i5 = csr[j + 5], i6 = csr[j + 6], i7 = csr[j + 7];
    uint4 v0 = X4[i0 * 16 + lane];
    uint4 v1 = X4[i1 * 16 + lane];
    uint4 v2 = X4[i2 * 16 + lane];
    uint4 v3 = X4[i3 * 16 + lane];
    uint4 v4 = X4[i4 * 16 + lane];
    uint4 v5 = X4[i5 * 16 + lane];
    uint4 v6 = X4[i6 * 16 + lane];
    uint4 v7 = X4[i7 * 16 + lane];
    add8(v0, aA); add8(v1, aA); add8(v2, aA); add8(v3, aA);
    add8(v4, aB); add8(v5, aB); add8(v6, aB); add8(v7, aB);
  }
  for (; j < e; ++j) {
    uint4 v = X4[csr[j] * 16 + lane];
    add8(v, aA);
  }

  float inv = 1.0f / fmaxf((float)(e - s), 1.0f);
  uint4 o;
  o.x = packbf2((aA[0] + aB[0]) * inv, (aA[1] + aB[1]) * inv);
  o.y = packbf2((aA[2] + aB[2]) * inv, (aA[3] + aB[3]) * inv);
  o.z = packbf2((aA[4] + aB[4]) * inv, (aA[5] + aB[5]) * inv);
  o.w = packbf2((aA[6] + aB[6]) * inv, (aA[7] + aB[7]) * inv);
  ((uint4*)outb)[n * 16 + lane] = o;
}

// ---------------- MFMA dual-GEMM: Out = relu(As*Ws + An*Wn + b) ----------------
// D layout (m89/m91-verified): col=lane&15 -> node, row=(lane>>4)*4+reg -> feat.

#define MFMA16(a, b, c) __builtin_amdgcn_mfma_f32_16x16x32_bf16((a), (b), (c), 0, 0, 0)

__global__ __launch_bounds__(256) void gemm_mfma(
    const uint* __restrict__ As_g, const uint* __restrict__ An_g,
    const uint4* __restrict__ Wp,   // pre-offset per layer
    const float* __restrict__ bias, uint* __restrict__ Out, int N) {
  int tid = threadIdx.x;
  int lane = tid & 63;
  int w = blockIdx.x * 4 + (tid >> 6);
  int ft = w & 7;
  int ng = w >> 3;
  int l15 = lane & 15, lhi = lane >> 4;

  short8 aH[2][4], aL[2][4];
#pragma unroll
  for (int m = 0; m < 2; ++m)
#pragma unroll
    for (int ks = 0; ks < 4; ++ks) {
      aH[m][ks] = as_short8(Wp[(m * 2 + 0) * 2048 + ft * 256 + ks * 64 + lane]);
      aL[m][ks] = as_short8(Wp[(m * 2 + 1) * 2048 + ft * 256 + ks * 64 + lane]);
    }
  int feat0 = ft * 16 + lhi * 4;
  float bv0 = bias[feat0], bv1 = bias[feat0 + 1];
  float bv2 = bias[feat0 + 2], bv3 = bias[feat0 + 3];

  const uint4* __restrict__ Xs = (const uint4*)As_g;
  const uint4* __restrict__ Xn = (const uint4*)An_g;

  for (int t = 0; t < 8; ++t) {
    int row = ng * 128 + t * 16 + l15;
    int rr = row < N ? row : N - 1;
    const uint4* ps = Xs + rr * 16 + lhi;
    const uint4* pn = Xn + rr * 16 + lhi;
    uint4 bs0 = ps[0], bs1 = ps[4], bs2 = ps[8], bs3 = ps[12];
    uint4 bn0 = pn[0], bn1 = pn[4], bn2 = pn[8], bn3 = pn[12];

    f32x4 acc = {0.f, 0.f, 0.f, 0.f};
    short8 b;
    b = as_short8(bs0); acc = MFMA16(aH[0][0], b, acc); acc = MFMA16(aL[0][0], b, acc);
    b = as_short8(bs1); acc = MFMA16(aH[0][1], b, acc); acc = MFMA16(aL[0][1], b, acc);
    b = as_short8(bs2); acc = MFMA16(aH[0][2], b, acc); acc = MFMA16(aL[0][2], b, acc);
    b = as_short8(bs3); acc = MFMA16(aH[0][3], b, acc); acc = MFMA16(aL[0][3], b, acc);
    b = as_short8(bn0); acc = MFMA16(aH[1][0], b, acc); acc = MFMA16(aL[1][0], b, acc);
    b = as_short8(bn1); acc = MFMA16(aH[1][1], b, acc); acc = MFMA16(aL[1][1], b, acc);
    b = as_short8(bn2); acc = MFMA16(aH[1][2], b, acc); acc = MFMA16(aL[1][2], b, acc);
    b = as_short8(bn3); acc = MFMA16(aH[1][3], b, acc); acc = MFMA16(aL[1][3], b, acc);

    float o0 = fmaxf(acc[0] + bv0, 0.f);
    float o1 = fmaxf(acc[1] + bv1, 0.f);
    float o2 = fmaxf(acc[2] + bv2, 0.f);
    float o3 = fmaxf(acc[3] + bv3, 0.f);
    if (row < N) {
      uint2 st;
      st.x = packbf2(o0, o1);
      st.y = packbf2(o2, o3);
      ((uint2*)Out)[row * 32 + ft * 4 + lhi] = st;
    }
  }
}

// ---------------- final FC via MFMA: bf16 [N,128] @ Wfc(padded 48) + b -> f32 ----
// Wave = one 16-node tile; A = Wfc^T fragments (hi/lo, 3 col-tiles x 4 k-steps),
// B = H rows (4 direct uint4 loads). D: col=lane&15 -> node, row -> fc-col.

__global__ __launch_bounds__(256) void fc_mfma(const uint* __restrict__ Hb,
                                               const uint4* __restrict__ Wfcp,
                                               const float* __restrict__ bg,
                                               float* __restrict__ Out, int N) {
  int tid = threadIdx.x;
  int lane = tid & 63;
  int t = blockIdx.x * 4 + (tid >> 6);    // node tile
  int l15 = lane & 15, lhi = lane >> 4;

  short8 aH[3][4], aL[3][4];
#pragma unroll
  for (int ct = 0; ct < 3; ++ct)
#pragma unroll
    for (int ks = 0; ks < 4; ++ks) {
      aH[ct][ks] = as_short8(Wfcp[((0 * 3 + ct) * 4 + ks) * 64 + lane]);
      aL[ct][ks] = as_short8(Wfcp[((1 * 3 + ct) * 4 + ks) * 64 + lane]);
    }

  int row = t * 16 + l15;
  int rr = row < N ? row : N - 1;
  const uint4* ph = ((const uint4*)Hb) + rr * 16 + lhi;
  uint4 b0 = ph[0], b1 = ph[4], b2 = ph[8], b3 = ph[12];
  short8 v0 = as_short8(b0), v1 = as_short8(b1), v2 = as_short8(b2), v3 = as_short8(b3);

  f32x4 acc[3];
#pragma unroll
  for (int ct = 0; ct < 3; ++ct) {
    f32x4 a = {0.f, 0.f, 0.f, 0.f};
    a = MFMA16(aH[ct][0], v0, a); a = MFMA16(aL[ct][0], v0, a);
    a = MFMA16(aH[ct][1], v1, a); a = MFMA16(aL[ct][1], v1, a);
    a = MFMA16(aH[ct][2], v2, a); a = MFMA16(aL[ct][2], v2, a);
    a = MFMA16(aH[ct][3], v3, a); a = MFMA16(aL[ct][3], v3, a);
    acc[ct] = a;
  }

  if (row < N) {
    float* orow = Out + (size_t)row * 47;
#pragma unroll
    for (int ct = 0; ct < 3; ++ct) {
      int col0 = ct * 16 + lhi * 4;
      if (col0 + 3 < 47) {
        f32x4u st;
        st[0] = acc[ct][0] + bg[col0];
        st[1] = acc[ct][1] + bg[col0 + 1];
        st[2] = acc[ct][2] + bg[col0 + 2];
        st[3] = acc[ct][3] + bg[col0 + 3];
        *(f32x4u*)(orow + col0) = st;
      } else {
#pragma unroll
        for (int r = 0; r < 4; ++r) {
          int col = col0 + r;
          if (col < 47) orow[col] = acc[ct][r] + bg[col];
        }
      }
    }
  }
}

// ---------------- launch ----------------

extern "C" void kernel_launch(void* const* d_in, const int* in_sizes, int n_in,
                              void* d_out, int out_size, void* d_ws, size_t ws_size,
                              hipStream_t stream) {
  const float* feat    = (const float*)d_in[0];
  const int*   src     = (const int*)d_in[1];
  const int*   dst     = (const int*)d_in[2];
  const float* Wself0  = (const float*)d_in[3];
  const float* Wneigh0 = (const float*)d_in[4];
  const float* b0      = (const float*)d_in[5];
  const float* Wself1  = (const float*)d_in[6];
  const float* Wneigh1 = (const float*)d_in[7];
  const float* b1      = (const float*)d_in[8];
  const float* Wfc     = (const float*)d_in[9];
  const float* bfc     = (const float*)d_in[10];
  float* out = (float*)d_out;

  // workspace (bytes); overlaps exploit liveness:
  //   gbuf dead after passB; featb dead after gemm0 -> h2b reuses featb's slot.
  char* w = (char*)d_ws;
  int*   offs    = (int*)(w);                 // (N+1) ints
  int*   bbase   = (int*)(w + 262144);        // NBUCK+1 ints
  int*   histA   = (int*)(w + 266240);        // NBA*NBUCK ints (~100 KB)
  int*   csr     = (int*)(w + 524288);        // E ints -> ends 6,924,288
  uint4* Wpack   = (uint4*)(w + 7340032);     // 17920 uint4 = 280 KB
  uint*  featb   = (uint*)(w + 7864320);      // N*64 uints (bf16)
  uint*  h2b     = (uint*)(w + 7864320);      // same region, after featb dead
  uint*  gbuf    = (uint*)(w + 20971520);     // E uints = 6.4 MB, dead after passB
  uint*  hnb     = (uint*)(w + 27787264);     // N*64 uints (bf16)
  uint*  h0b     = (uint*)(w + 41943040);     // N*64 uints (bf16)

  const int N = NN;

  histA_kernel<<<NBA, 1024, 0, stream>>>(dst, histA);
  scanA_kernel<<<1, 256, 0, stream>>>(histA, bbase);
  scatterA_kernel<<<NBA, 1024, 0, stream>>>(src, dst, histA, bbase, gbuf);
  passB_kernel<<<NBUCK, 1024, 0, stream>>>(gbuf, bbase, offs, csr);

  tobf16_kernel<<<(N * 16 + 255) / 256, 256, 0, stream>>>(feat, featb, N * 16);
  packW_kernel<<<70, 256, 0, stream>>>(Wself0, Wneigh0, Wself1, Wneigh1, Wfc, Wpack);

  const int gwaves = 8 * ((N + 127) / 128);          // 8 feat-tiles x node-groups
  const int gblocks_mfma = (gwaves + 3) / 4;         // 4 waves/block
  const int fcblocks = ((N + 15) / 16 + 3) / 4;      // 1 wave per 16-node tile

  agg_kernel<<<(N + 15) / 16, 256, 0, stream>>>(featb, csr, offs, hnb, N);
  gemm_mfma<<<gblocks_mfma, 256, 0, stream>>>(featb, hnb, Wpack, b0, h0b, N);
  agg_kernel<<<(N + 15) / 16, 256, 0, stream>>>(h0b, csr, offs, hnb, N);
  gemm_mfma<<<gblocks_mfma, 256, 0, stream>>>(h0b, hnb, Wpack + 8192, b1, h2b, N);
  fc_mfma<<<fcblocks, 256, 0, stream>>>(h2b, Wpack + 16384, bfc, out, N);
}

// Round 12
// 186.982 us; speedup vs baseline: 1.3583x; 1.2178x over previous
//
#include <hip/hip_runtime.h>

#define NN 50000
#define NE 1600000
#define NBA 128          // pass-A edge chunks (blocks)
#define CPB (NE / NBA)   // 12500 edges per chunk
#define NBUCK 196        // dst>>8 buckets (256 nodes each); 49999>>8 = 195
#define MAXBE 12288      // per-bucket edge cap: mean 8192, sigma~90 -> +45 sigma

typedef unsigned int uint;
typedef __attribute__((ext_vector_type(8))) short short8;   // 8 bf16 (4 VGPRs)
typedef __attribute__((ext_vector_type(4))) float f32x4;    // MFMA accumulator
typedef __attribute__((ext_vector_type(4), aligned(4))) float f32x4u;  // 4B-aligned store

// ---------------- bf16 helpers (packed pairs in uint32) ----------------

__device__ __forceinline__ uint bf16rne(float f) {
  uint u = __float_as_uint(f);
  return (u + 0x7fffu + ((u >> 16) & 1u)) >> 16;
}
__device__ __forceinline__ uint packbf2(float lo, float hi) {
  return bf16rne(lo) | (bf16rne(hi) << 16);
}
__device__ __forceinline__ float bflo(uint u) { return __uint_as_float(u << 16); }
__device__ __forceinline__ float bfhi(uint u) { return __uint_as_float(u & 0xffff0000u); }

__device__ __forceinline__ short8 as_short8(uint4 v) {
  union { uint4 u; short8 s; } cv; cv.u = v; return cv.s;
}

__device__ __forceinline__ void add8(const uint4 v, float* a) {
  a[0] += bflo(v.x); a[1] += bfhi(v.x);
  a[2] += bflo(v.y); a[3] += bfhi(v.y);
  a[4] += bflo(v.z); a[5] += bfhi(v.z);
  a[6] += bflo(v.w); a[7] += bfhi(v.w);
}

// f32 [n8*8] -> packed bf16 [n8 uint4]
__global__ __launch_bounds__(256) void tobf16_kernel(const float* __restrict__ in,
                                                     uint* __restrict__ outb, int n8) {
  int t = blockIdx.x * 256 + threadIdx.x;
  if (t < n8) {
    float4 a = ((const float4*)in)[2 * t];
    float4 b = ((const float4*)in)[2 * t + 1];
    uint4 o;
    o.x = packbf2(a.x, a.y);
    o.y = packbf2(a.z, a.w);
    o.z = packbf2(b.x, b.y);
    o.w = packbf2(b.z, b.w);
    ((uint4*)outb)[t] = o;
  }
}

// ---------------- pack weights into MFMA A-operand fragments ----------------
// A-operand = W^T tile: lane holds A[feat=ft*16+(lane&15)][k=ks*32+(lane>>4)*8+j].
// hi/lo split: W = W_hi(bf16) + W_lo(bf16 of residual) keeps f32-level accuracy.
// t < 16384: layer weights. t in [16384,17920): Wfc (cols padded 47->48).

__global__ __launch_bounds__(256) void packW_kernel(const float* __restrict__ W00,
                                                    const float* __restrict__ W01,
                                                    const float* __restrict__ W10,
                                                    const float* __restrict__ W11,
                                                    const float* __restrict__ Wfc,
                                                    uint4* __restrict__ Wpack) {
  int t = blockIdx.x * 256 + threadIdx.x;
  if (t < 16384) {
    int lane = t & 63;
    int ks   = (t >> 6) & 3;
    int ft   = (t >> 8) & 7;
    int part = (t >> 11) & 1;
    int mat  = (t >> 12) & 1;
    int layer= (t >> 13) & 1;
    const float* Wsrc = layer ? (mat ? W11 : W10) : (mat ? W01 : W00);
    int feat  = ft * 16 + (lane & 15);
    int kbase = ks * 32 + (lane >> 4) * 8;
    uint o[4];
#pragma unroll
    for (int h = 0; h < 4; ++h) {
      float w0 = Wsrc[(kbase + 2 * h) * 128 + feat];
      float w1 = Wsrc[(kbase + 2 * h + 1) * 128 + feat];
      uint h0 = bf16rne(w0), h1 = bf16rne(w1);
      uint v0, v1;
      if (part == 0) { v0 = h0; v1 = h1; }
      else {
        v0 = bf16rne(w0 - __uint_as_float(h0 << 16));
        v1 = bf16rne(w1 - __uint_as_float(h1 << 16));
      }
      o[h] = v0 | (v1 << 16);
    }
    uint4 r; r.x = o[0]; r.y = o[1]; r.z = o[2]; r.w = o[3];
    Wpack[t] = r;
  } else if (t < 16384 + 1536) {
    int tt = t - 16384;
    int lane = tt & 63;
    int ks   = (tt >> 6) & 3;
    int ct   = (tt >> 8) % 3;
    int part = tt / 768;
    int col  = ct * 16 + (lane & 15);
    int kbase = ks * 32 + (lane >> 4) * 8;
    uint o[4];
#pragma unroll
    for (int h = 0; h < 4; ++h) {
      float w0 = (col < 47) ? Wfc[(kbase + 2 * h) * 47 + col] : 0.f;
      float w1 = (col < 47) ? Wfc[(kbase + 2 * h + 1) * 47 + col] : 0.f;
      uint h0 = bf16rne(w0), h1 = bf16rne(w1);
      uint v0, v1;
      if (part == 0) { v0 = h0; v1 = h1; }
      else {
        v0 = bf16rne(w0 - __uint_as_float(h0 << 16));
        v1 = bf16rne(w1 - __uint_as_float(h1 << 16));
      }
      o[h] = v0 | (v1 << 16);
    }
    uint4 r; r.x = o[0]; r.y = o[1]; r.z = o[2]; r.w = o[3];
    Wpack[t] = r;
  }
}

// ---------------- CSR build: two-level bucket sort, all writes coalesced --------
// bucket(d) = d >> 8 (256 nodes / bucket, NBUCK=196).

__global__ __launch_bounds__(1024) void histA_kernel(const int* __restrict__ dst,
                                                     int* __restrict__ histA) {
  __shared__ int h[NBUCK];
  int tid = threadIdx.x, b = blockIdx.x;
  if (tid < NBUCK) h[tid] = 0;
  __syncthreads();
  const int4* d4 = (const int4*)(dst + b * CPB);
  for (int i = tid; i < CPB / 4; i += 1024) {
    int4 d = d4[i];
    atomicAdd(&h[d.x >> 8], 1);
    atomicAdd(&h[d.y >> 8], 1);
    atomicAdd(&h[d.z >> 8], 1);
    atomicAdd(&h[d.w >> 8], 1);
  }
  __syncthreads();
  if (tid < NBUCK) histA[b * NBUCK + tid] = h[tid];
}

__global__ __launch_bounds__(256) void scanA_kernel(int* __restrict__ histA,
                                                    int* __restrict__ bucket_base) {
  __shared__ int wsum[4];
  int t = threadIdx.x;
  int s = 0;
  if (t < NBUCK) {
#pragma unroll 8
    for (int b = 0; b < NBA; ++b) {
      int v = histA[b * NBUCK + t];
      histA[b * NBUCK + t] = s;
      s += v;
    }
  }
  int lane = t & 63, wid = t >> 6;
  int x = s;
#pragma unroll
  for (int d = 1; d < 64; d <<= 1) {
    int y = __shfl_up(x, d, 64);
    if (lane >= d) x += y;
  }
  if (lane == 63) wsum[wid] = x;
  __syncthreads();
  int woff = 0;
  if (wid > 0) woff += wsum[0];
  if (wid > 1) woff += wsum[1];
  if (wid > 2) woff += wsum[2];
  int excl = woff + x - s;
  if (t < NBUCK) bucket_base[t] = excl;
  if (t == NBUCK - 1) bucket_base[NBUCK] = excl + s;
}

__global__ __launch_bounds__(1024) void scatterA_kernel(const int* __restrict__ src,
                                                        const int* __restrict__ dst,
                                                        const int* __restrict__ histA,
                                                        const int* __restrict__ bucket_base,
                                                        uint* __restrict__ gbuf) {
  __shared__ int cur[NBUCK];
  int tid = threadIdx.x, b = blockIdx.x;
  if (tid < NBUCK) cur[tid] = histA[b * NBUCK + tid] + bucket_base[tid];
  __syncthreads();
  const int4* d4 = (const int4*)(dst + b * CPB);
  const int4* s4 = (const int4*)(src + b * CPB);
  for (int i = tid; i < CPB / 4; i += 1024) {
    int4 d = d4[i];
    int4 s = s4[i];
    int p0 = atomicAdd(&cur[d.x >> 8], 1);
    int p1 = atomicAdd(&cur[d.y >> 8], 1);
    int p2 = atomicAdd(&cur[d.z >> 8], 1);
    int p3 = atomicAdd(&cur[d.w >> 8], 1);
    gbuf[p0] = (uint)s.x | ((uint)(d.x & 255) << 16);
    gbuf[p1] = (uint)s.y | ((uint)(d.y & 255) << 16);
    gbuf[p2] = (uint)s.z | ((uint)(d.z & 255) << 16);
    gbuf[p3] = (uint)s.w | ((uint)(d.w & 255) << 16);
  }
}

__global__ __launch_bounds__(1024) void passB_kernel(const uint* __restrict__ gbuf,
                                                     const int* __restrict__ bucket_base,
                                                     int* __restrict__ offs,
                                                     int* __restrict__ csr) {
  __shared__ int cnt_l[256];
  __shared__ int cur_l[256];
  __shared__ int wsum[4];
  int tid = threadIdx.x, b = blockIdx.x;
  int bbase = bucket_base[b];
  int nE = bucket_base[b + 1] - bbase;
  int lo = b << 8;
  if (tid < 256) cnt_l[tid] = 0;
  __syncthreads();

  const uint* gptr = gbuf + bbase;
  uint pv[MAXBE / 1024];
#pragma unroll
  for (int j = 0; j < MAXBE / 1024; ++j) {
    int i = tid + j * 1024;
    if (i < nE) {
      uint p = gptr[i];
      pv[j] = p;
      atomicAdd(&cnt_l[(p >> 16) & 255], 1);
    }
  }
  __syncthreads();

  int excl = 0, v = 0;
  if (tid < 256) {
    v = cnt_l[tid];
    int lane = tid & 63, wid = tid >> 6;
    int x = v;
#pragma unroll
    for (int d = 1; d < 64; d <<= 1) {
      int y = __shfl_up(x, d, 64);
      if (lane >= d) x += y;
    }
    if (lane == 63) wsum[wid] = x;
    __syncthreads();
    int woff = 0;
    if (wid > 0) woff += wsum[0];
    if (wid > 1) woff += wsum[1];
    if (wid > 2) woff += wsum[2];
    excl = woff + x - v;
    cur_l[tid] = excl;
    int node = lo + tid;
    if (node <= NN) offs[node] = bbase + excl;   // covers offs[0..NN] across buckets
  } else {
    __syncthreads();
  }
  __syncthreads();

#pragma unroll
  for (int j = 0; j < MAXBE / 1024; ++j) {
    int i = tid + j * 1024;
    if (i < nE) {
      uint p = pv[j];
      int r = atomicAdd(&cur_l[(p >> 16) & 255], 1);
      csr[bbase + r] = (int)(p & 0xFFFFu);
    }
  }
}

// ---------------- segment mean over packed-bf16 rows (proven round-8 form) -------
// 256 threads = 16 nodes/block; 16 lanes per node, uint4 = 8 dims per lane.

__global__ __launch_bounds__(256) void agg_kernel(const uint* __restrict__ Xb,
                                                  const int* __restrict__ csr,
                                                  const int* __restrict__ offs,
                                                  uint* __restrict__ outb, int N) {
  const uint4* __restrict__ X4 = (const uint4*)Xb;  // 16 uint4 per 128-dim row
  int tid = threadIdx.x;
  int slot = tid >> 4;
  int lane = tid & 15;
  int n = blockIdx.x * 16 + slot;
  if (n >= N) return;
  int s = offs[n], e = offs[n + 1];

  float aA[8] = {0.f, 0.f, 0.f, 0.f, 0.f, 0.f, 0.f, 0.f};
  float aB[8] = {0.f, 0.f, 0.f, 0.f, 0.f, 0.f, 0.f, 0.f};

  int j = s;
  for (; j + 8 <= e; j += 8) {
    int i0 = csr[j + 0], i1 = csr[j + 1], i2 = csr[j + 2], i3 = csr[j + 3];
    int i4 = csr[j + 4], i5 = csr[j + 5], i6 = csr[j + 6], i7 = csr[j + 7];
    uint4 v0 = X4[i0 * 16 + lane];
    uint4 v1 = X4[i1 * 16 + lane];
    uint4 v2 = X4[i2 * 16 + lane];
    uint4 v3 = X4[i3 * 16 + lane];
    uint4 v4 = X4[i4 * 16 + lane];
    uint4 v5 = X4[i5 * 16 + lane];
    uint4 v6 = X4[i6 * 16 + lane];
    uint4 v7 = X4[i7 * 16 + lane];
    add8(v0, aA); add8(v1, aA); add8(v2, aA); add8(v3, aA);
    add8(v4, aB); add8(v5, aB); add8(v6, aB); add8(v7, aB);
  }
  for (; j < e; ++j) {
    uint4 v = X4[csr[j] * 16 + lane];
    add8(v, aA);
  }

  float inv = 1.0f / fmaxf((float)(e - s), 1.0f);
  uint4 o;
  o.x = packbf2((aA[0] + aB[0]) * inv, (aA[1] + aB[1]) * inv);
  o.y = packbf2((aA[2] + aB[2]) * inv, (aA[3] + aB[3]) * inv);
  o.z = packbf2((aA[4] + aB[4]) * inv, (aA[5] + aB[5]) * inv);
  o.w = packbf2((aA[6] + aB[6]) * inv, (aA[7] + aB[7]) * inv);
  ((uint4*)outb)[n * 16 + lane] = o;
}

// ---------------- MFMA dual-GEMM, LDS-staged: Out = relu(As*Ws + An*Wn + b) ------
// Block = 512 threads = 8 waves = ft 0..7, all sharing one 128-node group.
// Per 16-node tile: cooperative coalesced load of As+An rows into padded LDS
// (512 uint4 = one per thread), barrier, each wave does 16 MFMAs from
// ds_read_b128 fragments (row pad 17 uint4 -> 2-way bank alias, free), barrier.
// Global B-traffic = 1x (was 8x: each row re-read per ft-wave).
// D layout (m89/m91-verified): col=lane&15 -> node, row=(lane>>4)*4+reg -> feat.

#define MFMA16(a, b, c) __builtin_amdgcn_mfma_f32_16x16x32_bf16((a), (b), (c), 0, 0, 0)

__global__ __launch_bounds__(512) void gemm_mfma(
    const uint* __restrict__ As_g, const uint* __restrict__ An_g,
    const uint4* __restrict__ Wp,   // pre-offset per layer
    const float* __restrict__ bias, uint* __restrict__ Out, int N) {
  __shared__ uint4 sT[2][16][17];   // [mat][row][16 uint4 + pad]
  int tid = threadIdx.x;
  int lane = tid & 63;
  int ft = tid >> 6;                // wave id = feat tile
  int ng = blockIdx.x;
  int l15 = lane & 15, lhi = lane >> 4;

  short8 aH[2][4], aL[2][4];
#pragma unroll
  for (int m = 0; m < 2; ++m)
#pragma unroll
    for (int ks = 0; ks < 4; ++ks) {
      aH[m][ks] = as_short8(Wp[(m * 2 + 0) * 2048 + ft * 256 + ks * 64 + lane]);
      aL[m][ks] = as_short8(Wp[(m * 2 + 1) * 2048 + ft * 256 + ks * 64 + lane]);
    }
  int feat0 = ft * 16 + lhi * 4;
  float bv0 = bias[feat0], bv1 = bias[feat0 + 1];
  float bv2 = bias[feat0 + 2], bv3 = bias[feat0 + 3];

  const uint4* __restrict__ Xs = (const uint4*)As_g;
  const uint4* __restrict__ Xn = (const uint4*)An_g;

  // staging coords: thread loads one uint4 per tile
  int smat = tid >> 8;              // 0 = As, 1 = An
  int sidx = tid & 255;
  int srow = sidx >> 4;             // 0..15
  int scol = sidx & 15;             // 0..15

  for (int t = 0; t < 8; ++t) {
    int grow = ng * 128 + t * 16 + srow;
    if (grow >= N) grow = N - 1;
    const uint4* srcp = smat ? Xn : Xs;
    sT[smat][srow][scol] = srcp[grow * 16 + scol];
    __syncthreads();

    f32x4 acc = {0.f, 0.f, 0.f, 0.f};
    short8 b;
#pragma unroll
    for (int ks = 0; ks < 4; ++ks) {
      b = as_short8(sT[0][l15][ks * 4 + lhi]);
      acc = MFMA16(aH[0][ks], b, acc);
      acc = MFMA16(aL[0][ks], b, acc);
    }
#pragma unroll
    for (int ks = 0; ks < 4; ++ks) {
      b = as_short8(sT[1][l15][ks * 4 + lhi]);
      acc = MFMA16(aH[1][ks], b, acc);
      acc = MFMA16(aL[1][ks], b, acc);
    }

    int row = ng * 128 + t * 16 + l15;
    float o0 = fmaxf(acc[0] + bv0, 0.f);
    float o1 = fmaxf(acc[1] + bv1, 0.f);
    float o2 = fmaxf(acc[2] + bv2, 0.f);
    float o3 = fmaxf(acc[3] + bv3, 0.f);
    if (row < N) {
      uint2 st;
      st.x = packbf2(o0, o1);
      st.y = packbf2(o2, o3);
      ((uint2*)Out)[row * 32 + ft * 4 + lhi] = st;
    }
    __syncthreads();
  }
}

// ---------------- final FC via MFMA: bf16 [N,128] @ Wfc(padded 48) + b -> f32 ----

__global__ __launch_bounds__(256) void fc_mfma(const uint* __restrict__ Hb,
                                               const uint4* __restrict__ Wfcp,
                                               const float* __restrict__ bg,
                                               float* __restrict__ Out, int N) {
  int tid = threadIdx.x;
  int lane = tid & 63;
  int t = blockIdx.x * 4 + (tid >> 6);    // node tile
  int l15 = lane & 15, lhi = lane >> 4;

  short8 aH[3][4], aL[3][4];
#pragma unroll
  for (int ct = 0; ct < 3; ++ct)
#pragma unroll
    for (int ks = 0; ks < 4; ++ks) {
      aH[ct][ks] = as_short8(Wfcp[((0 * 3 + ct) * 4 + ks) * 64 + lane]);
      aL[ct][ks] = as_short8(Wfcp[((1 * 3 + ct) * 4 + ks) * 64 + lane]);
    }

  int row = t * 16 + l15;
  int rr = row < N ? row : N - 1;
  const uint4* ph = ((const uint4*)Hb) + rr * 16 + lhi;
  uint4 b0 = ph[0], b1 = ph[4], b2 = ph[8], b3 = ph[12];
  short8 v0 = as_short8(b0), v1 = as_short8(b1), v2 = as_short8(b2), v3 = as_short8(b3);

  f32x4 acc[3];
#pragma unroll
  for (int ct = 0; ct < 3; ++ct) {
    f32x4 a = {0.f, 0.f, 0.f, 0.f};
    a = MFMA16(aH[ct][0], v0, a); a = MFMA16(aL[ct][0], v0, a);
    a = MFMA16(aH[ct][1], v1, a); a = MFMA16(aL[ct][1], v1, a);
    a = MFMA16(aH[ct][2], v2, a); a = MFMA16(aL[ct][2], v2, a);
    a = MFMA16(aH[ct][3], v3, a); a = MFMA16(aL[ct][3], v3, a);
    acc[ct] = a;
  }

  if (row < N) {
    float* orow = Out + (size_t)row * 47;
#pragma unroll
    for (int ct = 0; ct < 3; ++ct) {
      int col0 = ct * 16 + lhi * 4;
      if (col0 + 3 < 47) {
        f32x4u st;
        st[0] = acc[ct][0] + bg[col0];
        st[1] = acc[ct][1] + bg[col0 + 1];
        st[2] = acc[ct][2] + bg[col0 + 2];
        st[3] = acc[ct][3] + bg[col0 + 3];
        *(f32x4u*)(orow + col0) = st;
      } else {
#pragma unroll
        for (int r = 0; r < 4; ++r) {
          int col = col0 + r;
          if (col < 47) orow[col] = acc[ct][r] + bg[col];
        }
      }
    }
  }
}

// ---------------- launch ----------------

extern "C" void kernel_launch(void* const* d_in, const int* in_sizes, int n_in,
                              void* d_out, int out_size, void* d_ws, size_t ws_size,
                              hipStream_t stream) {
  const float* feat    = (const float*)d_in[0];
  const int*   src     = (const int*)d_in[1];
  const int*   dst     = (const int*)d_in[2];
  const float* Wself0  = (const float*)d_in[3];
  const float* Wneigh0 = (const float*)d_in[4];
  const float* b0      = (const float*)d_in[5];
  const float* Wself1  = (const float*)d_in[6];
  const float* Wneigh1 = (const float*)d_in[7];
  const float* b1      = (const float*)d_in[8];
  const float* Wfc     = (const float*)d_in[9];
  const float* bfc     = (const float*)d_in[10];
  float* out = (float*)d_out;

  // workspace (bytes); overlaps exploit liveness:
  //   gbuf dead after passB; featb dead after gemm0 -> h2b reuses featb's slot.
  char* w = (char*)d_ws;
  int*   offs    = (int*)(w);                 // (N+1) ints
  int*   bbase   = (int*)(w + 262144);        // NBUCK+1 ints
  int*   histA   = (int*)(w + 266240);        // NBA*NBUCK ints (~100 KB)
  int*   csr     = (int*)(w + 524288);        // E ints -> ends 6,924,288
  uint4* Wpack   = (uint4*)(w + 7340032);     // 17920 uint4 = 280 KB
  uint*  featb   = (uint*)(w + 7864320);      // N*64 uints (bf16)
  uint*  h2b     = (uint*)(w + 7864320);      // same region, after featb dead
  uint*  gbuf    = (uint*)(w + 20971520);     // E uints = 6.4 MB, dead after passB
  uint*  hnb     = (uint*)(w + 27787264);     // N*64 uints (bf16)
  uint*  h0b     = (uint*)(w + 41943040);     // N*64 uints (bf16)

  const int N = NN;

  histA_kernel<<<NBA, 1024, 0, stream>>>(dst, histA);
  scanA_kernel<<<1, 256, 0, stream>>>(histA, bbase);
  scatterA_kernel<<<NBA, 1024, 0, stream>>>(src, dst, histA, bbase, gbuf);
  passB_kernel<<<NBUCK, 1024, 0, stream>>>(gbuf, bbase, offs, csr);

  tobf16_kernel<<<(N * 16 + 255) / 256, 256, 0, stream>>>(feat, featb, N * 16);
  packW_kernel<<<70, 256, 0, stream>>>(Wself0, Wneigh0, Wself1, Wneigh1, Wfc, Wpack);

  const int gblocks = (N + 127) / 128;               // 8-wave blocks, 128 nodes each
  const int fcblocks = ((N + 15) / 16 + 3) / 4;      // 1 wave per 16-node tile

  agg_kernel<<<(N + 15) / 16, 256, 0, stream>>>(featb, csr, offs, hnb, N);
  gemm_mfma<<<gblocks, 512, 0, stream>>>(featb, hnb, Wpack, b0, h0b, N);
  agg_kernel<<<(N + 15) / 16, 256, 0, stream>>>(h0b, csr, offs, hnb, N);
  gemm_mfma<<<gblocks, 512, 0, stream>>>(h0b, hnb, Wpack + 8192, b1, h2b, N);
  fc_mfma<<<fcblocks, 256, 0, stream>>>(h2b, Wpack + 16384, bfc, out, N);
}

// Round 13
// 183.002 us; speedup vs baseline: 1.3878x; 1.0217x over previous
//
#include <hip/hip_runtime.h>

#define NN 50000
#define NE 1600000
#define NBA 200          // pass-A edge chunks (blocks); CPB must be /4
#define CPB (NE / NBA)   // 8000 edges per chunk
#define NBUCK 196        // dst>>8 buckets (256 nodes each); 49999>>8 = 195
#define MAXBE 12288      // per-bucket edge cap: mean 8192, sigma~90 -> +45 sigma

typedef unsigned int uint;
typedef __attribute__((ext_vector_type(8))) short short8;   // 8 bf16 (4 VGPRs)
typedef __attribute__((ext_vector_type(4))) float f32x4;    // MFMA accumulator
typedef __attribute__((ext_vector_type(4), aligned(4))) float f32x4u;  // 4B-aligned store

// ---------------- bf16 helpers (packed pairs in uint32) ----------------

__device__ __forceinline__ uint bf16rne(float f) {
  uint u = __float_as_uint(f);
  return (u + 0x7fffu + ((u >> 16) & 1u)) >> 16;
}
__device__ __forceinline__ uint packbf2(float lo, float hi) {
  return bf16rne(lo) | (bf16rne(hi) << 16);
}
__device__ __forceinline__ float bflo(uint u) { return __uint_as_float(u << 16); }
__device__ __forceinline__ float bfhi(uint u) { return __uint_as_float(u & 0xffff0000u); }

__device__ __forceinline__ short8 as_short8(uint4 v) {
  union { uint4 u; short8 s; } cv; cv.u = v; return cv.s;
}

__device__ __forceinline__ void add8(const uint4 v, float* a) {
  a[0] += bflo(v.x); a[1] += bfhi(v.x);
  a[2] += bflo(v.y); a[3] += bfhi(v.y);
  a[4] += bflo(v.z); a[5] += bfhi(v.z);
  a[6] += bflo(v.w); a[7] += bfhi(v.w);
}

// f32 [n8*8] -> packed bf16 [n8 uint4]
__global__ __launch_bounds__(256) void tobf16_kernel(const float* __restrict__ in,
                                                     uint* __restrict__ outb, int n8) {
  int t = blockIdx.x * 256 + threadIdx.x;
  if (t < n8) {
    float4 a = ((const float4*)in)[2 * t];
    float4 b = ((const float4*)in)[2 * t + 1];
    uint4 o;
    o.x = packbf2(a.x, a.y);
    o.y = packbf2(a.z, a.w);
    o.z = packbf2(b.x, b.y);
    o.w = packbf2(b.z, b.w);
    ((uint4*)outb)[t] = o;
  }
}

// ---------------- pack weights into MFMA A-operand fragments ----------------
// A-operand = W^T tile: lane holds A[feat=ft*16+(lane&15)][k=ks*32+(lane>>4)*8+j].
// hi/lo split: W = W_hi(bf16) + W_lo(bf16 of residual) keeps f32-level accuracy.
// t < 16384: layer weights. t in [16384,17920): Wfc (cols padded 47->48).

__global__ __launch_bounds__(256) void packW_kernel(const float* __restrict__ W00,
                                                    const float* __restrict__ W01,
                                                    const float* __restrict__ W10,
                                                    const float* __restrict__ W11,
                                                    const float* __restrict__ Wfc,
                                                    uint4* __restrict__ Wpack) {
  int t = blockIdx.x * 256 + threadIdx.x;
  if (t < 16384) {
    int lane = t & 63;
    int ks   = (t >> 6) & 3;
    int ft   = (t >> 8) & 7;
    int part = (t >> 11) & 1;
    int mat  = (t >> 12) & 1;
    int layer= (t >> 13) & 1;
    const float* Wsrc = layer ? (mat ? W11 : W10) : (mat ? W01 : W00);
    int feat  = ft * 16 + (lane & 15);
    int kbase = ks * 32 + (lane >> 4) * 8;
    uint o[4];
#pragma unroll
    for (int h = 0; h < 4; ++h) {
      float w0 = Wsrc[(kbase + 2 * h) * 128 + feat];
      float w1 = Wsrc[(kbase + 2 * h + 1) * 128 + feat];
      uint h0 = bf16rne(w0), h1 = bf16rne(w1);
      uint v0, v1;
      if (part == 0) { v0 = h0; v1 = h1; }
      else {
        v0 = bf16rne(w0 - __uint_as_float(h0 << 16));
        v1 = bf16rne(w1 - __uint_as_float(h1 << 16));
      }
      o[h] = v0 | (v1 << 16);
    }
    uint4 r; r.x = o[0]; r.y = o[1]; r.z = o[2]; r.w = o[3];
    Wpack[t] = r;
  } else if (t < 16384 + 1536) {
    int tt = t - 16384;
    int lane = tt & 63;
    int ks   = (tt >> 6) & 3;
    int ct   = (tt >> 8) % 3;
    int part = tt / 768;
    int col  = ct * 16 + (lane & 15);
    int kbase = ks * 32 + (lane >> 4) * 8;
    uint o[4];
#pragma unroll
    for (int h = 0; h < 4; ++h) {
      float w0 = (col < 47) ? Wfc[(kbase + 2 * h) * 47 + col] : 0.f;
      float w1 = (col < 47) ? Wfc[(kbase + 2 * h + 1) * 47 + col] : 0.f;
      uint h0 = bf16rne(w0), h1 = bf16rne(w1);
      uint v0, v1;
      if (part == 0) { v0 = h0; v1 = h1; }
      else {
        v0 = bf16rne(w0 - __uint_as_float(h0 << 16));
        v1 = bf16rne(w1 - __uint_as_float(h1 << 16));
      }
      o[h] = v0 | (v1 << 16);
    }
    uint4 r; r.x = o[0]; r.y = o[1]; r.z = o[2]; r.w = o[3];
    Wpack[t] = r;
  }
}

// ---------------- CSR build: two-level bucket sort, all writes coalesced --------
// bucket(d) = d >> 8 (256 nodes / bucket, NBUCK=196).

__global__ __launch_bounds__(1024) void histA_kernel(const int* __restrict__ dst,
                                                     int* __restrict__ histA) {
  __shared__ int h[NBUCK];
  int tid = threadIdx.x, b = blockIdx.x;
  if (tid < NBUCK) h[tid] = 0;
  __syncthreads();
  const int4* d4 = (const int4*)(dst + b * CPB);
  for (int i = tid; i < CPB / 4; i += 1024) {
    int4 d = d4[i];
    atomicAdd(&h[d.x >> 8], 1);
    atomicAdd(&h[d.y >> 8], 1);
    atomicAdd(&h[d.z >> 8], 1);
    atomicAdd(&h[d.w >> 8], 1);
  }
  __syncthreads();
  if (tid < NBUCK) histA[b * NBUCK + tid] = h[tid];
}

__global__ __launch_bounds__(256) void scanA_kernel(int* __restrict__ histA,
                                                    int* __restrict__ bucket_base) {
  __shared__ int wsum[4];
  int t = threadIdx.x;
  int s = 0;
  if (t < NBUCK) {
#pragma unroll 8
    for (int b = 0; b < NBA; ++b) {
      int v = histA[b * NBUCK + t];
      histA[b * NBUCK + t] = s;
      s += v;
    }
  }
  int lane = t & 63, wid = t >> 6;
  int x = s;
#pragma unroll
  for (int d = 1; d < 64; d <<= 1) {
    int y = __shfl_up(x, d, 64);
    if (lane >= d) x += y;
  }
  if (lane == 63) wsum[wid] = x;
  __syncthreads();
  int woff = 0;
  if (wid > 0) woff += wsum[0];
  if (wid > 1) woff += wsum[1];
  if (wid > 2) woff += wsum[2];
  int excl = woff + x - s;
  if (t < NBUCK) bucket_base[t] = excl;
  if (t == NBUCK - 1) bucket_base[NBUCK] = excl + s;
}

__global__ __launch_bounds__(1024) void scatterA_kernel(const int* __restrict__ src,
                                                        const int* __restrict__ dst,
                                                        const int* __restrict__ histA,
                                                        const int* __restrict__ bucket_base,
                                                        uint* __restrict__ gbuf) {
  __shared__ int cur[NBUCK];
  int tid = threadIdx.x, b = blockIdx.x;
  if (tid < NBUCK) cur[tid] = histA[b * NBUCK + tid] + bucket_base[tid];
  __syncthreads();
  const int4* d4 = (const int4*)(dst + b * CPB);
  const int4* s4 = (const int4*)(src + b * CPB);
  for (int i = tid; i < CPB / 4; i += 1024) {
    int4 d = d4[i];
    int4 s = s4[i];
    int p0 = atomicAdd(&cur[d.x >> 8], 1);
    int p1 = atomicAdd(&cur[d.y >> 8], 1);
    int p2 = atomicAdd(&cur[d.z >> 8], 1);
    int p3 = atomicAdd(&cur[d.w >> 8], 1);
    gbuf[p0] = (uint)s.x | ((uint)(d.x & 255) << 16);
    gbuf[p1] = (uint)s.y | ((uint)(d.y & 255) << 16);
    gbuf[p2] = (uint)s.z | ((uint)(d.z & 255) << 16);
    gbuf[p3] = (uint)s.w | ((uint)(d.w & 255) << 16);
  }
}

__global__ __launch_bounds__(1024) void passB_kernel(const uint* __restrict__ gbuf,
                                                     const int* __restrict__ bucket_base,
                                                     int* __restrict__ offs,
                                                     int* __restrict__ csr) {
  __shared__ int cnt_l[256];
  __shared__ int cur_l[256];
  __shared__ int wsum[4];
  int tid = threadIdx.x, b = blockIdx.x;
  int bbase = bucket_base[b];
  int nE = bucket_base[b + 1] - bbase;
  int lo = b << 8;
  if (tid < 256) cnt_l[tid] = 0;
  __syncthreads();

  const uint* gptr = gbuf + bbase;
  uint pv[MAXBE / 1024];
#pragma unroll
  for (int j = 0; j < MAXBE / 1024; ++j) {
    int i = tid + j * 1024;
    if (i < nE) {
      uint p = gptr[i];
      pv[j] = p;
      atomicAdd(&cnt_l[(p >> 16) & 255], 1);
    }
  }
  __syncthreads();

  int excl = 0, v = 0;
  if (tid < 256) {
    v = cnt_l[tid];
    int lane = tid & 63, wid = tid >> 6;
    int x = v;
#pragma unroll
    for (int d = 1; d < 64; d <<= 1) {
      int y = __shfl_up(x, d, 64);
      if (lane >= d) x += y;
    }
    if (lane == 63) wsum[wid] = x;
    __syncthreads();
    int woff = 0;
    if (wid > 0) woff += wsum[0];
    if (wid > 1) woff += wsum[1];
    if (wid > 2) woff += wsum[2];
    excl = woff + x - v;
    cur_l[tid] = excl;
    int node = lo + tid;
    if (node <= NN) offs[node] = bbase + excl;   // covers offs[0..NN] across buckets
  } else {
    __syncthreads();
  }
  __syncthreads();

#pragma unroll
  for (int j = 0; j < MAXBE / 1024; ++j) {
    int i = tid + j * 1024;
    if (i < nE) {
      uint p = pv[j];
      int r = atomicAdd(&cur_l[(p >> 16) & 255], 1);
      csr[bbase + r] = (int)(p & 0xFFFFu);
    }
  }
}

// ---------------- segment mean over packed-bf16 rows (proven round-8 form) -------
// 256 threads = 16 nodes/block; 16 lanes per node, uint4 = 8 dims per lane.

__global__ __launch_bounds__(256) void agg_kernel(const uint* __restrict__ Xb,
                                                  const int* __restrict__ csr,
                                                  const int* __restrict__ offs,
                                                  uint* __restrict__ outb, int N) {
  const uint4* __restrict__ X4 = (const uint4*)Xb;  // 16 uint4 per 128-dim row
  int tid = threadIdx.x;
  int slot = tid >> 4;
  int lane = tid & 15;
  int n = blockIdx.x * 16 + slot;
  if (n >= N) return;
  int s = offs[n], e = offs[n + 1];

  float aA[8] = {0.f, 0.f, 0.f, 0.f, 0.f, 0.f, 0.f, 0.f};
  float aB[8] = {0.f, 0.f, 0.f, 0.f, 0.f, 0.f, 0.f, 0.f};

  int j = s;
  for (; j + 8 <= e; j += 8) {
    int i0 = csr[j + 0], i1 = csr[j + 1], i2 = csr[j + 2], i3 = csr[j + 3];
    int i4 = csr[j + 4], i5 = csr[j + 5], i6 = csr[j + 6], i7 = csr[j + 7];
    uint4 v0 = X4[i0 * 16 + lane];
    uint4 v1 = X4[i1 * 16 + lane];
    uint4 v2 = X4[i2 * 16 + lane];
    uint4 v3 = X4[i3 * 16 + lane];
    uint4 v4 = X4[i4 * 16 + lane];
    uint4 v5 = X4[i5 * 16 + lane];
    uint4 v6 = X4[i6 * 16 + lane];
    uint4 v7 = X4[i7 * 16 + lane];
    add8(v0, aA); add8(v1, aA); add8(v2, aA); add8(v3, aA);
    add8(v4, aB); add8(v5, aB); add8(v6, aB); add8(v7, aB);
  }
  for (; j < e; ++j) {
    uint4 v = X4[csr[j] * 16 + lane];
    add8(v, aA);
  }

  float inv = 1.0f / fmaxf((float)(e - s), 1.0f);
  uint4 o;
  o.x = packbf2((aA[0] + aB[0]) * inv, (aA[1] + aB[1]) * inv);
  o.y = packbf2((aA[2] + aB[2]) * inv, (aA[3] + aB[3]) * inv);
  o.z = packbf2((aA[4] + aB[4]) * inv, (aA[5] + aB[5]) * inv);
  o.w = packbf2((aA[6] + aB[6]) * inv, (aA[7] + aB[7]) * inv);
  ((uint4*)outb)[n * 16 + lane] = o;
}

// ---------------- MFMA dual-GEMM, LDS-staged, optional fused final FC ------------
// Block = 512 threads = 8 waves = ft 0..7, sharing one 128-node group.
// Per 16-node tile: coalesced cooperative load into padded LDS, barrier,
// 16 MFMAs per wave from ds_read_b128 fragments, barrier.
// do_fc: epilogue goes to LDS h2s[128][17] uint4 (68-word stride -> 4-bank
// rotate, 2-way = free) instead of global; after the loop each wave runs the
// 47-col FC MFMA for its own 16-node tile and writes f32 output directly.
// D layout (m89/m91-verified): col=lane&15 -> node, row=(lane>>4)*4+reg -> feat.

#define MFMA16(a, b, c) __builtin_amdgcn_mfma_f32_16x16x32_bf16((a), (b), (c), 0, 0, 0)

__global__ __launch_bounds__(512) void gemm_mfma(
    const uint* __restrict__ As_g, const uint* __restrict__ An_g,
    const uint4* __restrict__ Wp,   // pre-offset per layer
    const float* __restrict__ bias, uint* __restrict__ Out,
    const uint4* __restrict__ Wfcp, const float* __restrict__ bfc,
    float* __restrict__ OutFC, int do_fc, int N) {
  __shared__ uint4 sT[2][16][17];   // staging: [mat][row][16 uint4 + pad]
  __shared__ uint4 h2s[128][17];    // fused-fc H rows (bf16), padded
  int tid = threadIdx.x;
  int lane = tid & 63;
  int ft = tid >> 6;                // wave id = feat tile
  int ng = blockIdx.x;
  int l15 = lane & 15, lhi = lane >> 4;

  short8 aH[2][4], aL[2][4];
#pragma unroll
  for (int m = 0; m < 2; ++m)
#pragma unroll
    for (int ks = 0; ks < 4; ++ks) {
      aH[m][ks] = as_short8(Wp[(m * 2 + 0) * 2048 + ft * 256 + ks * 64 + lane]);
      aL[m][ks] = as_short8(Wp[(m * 2 + 1) * 2048 + ft * 256 + ks * 64 + lane]);
    }
  int feat0 = ft * 16 + lhi * 4;
  float bv0 = bias[feat0], bv1 = bias[feat0 + 1];
  float bv2 = bias[feat0 + 2], bv3 = bias[feat0 + 3];

  const uint4* __restrict__ Xs = (const uint4*)As_g;
  const uint4* __restrict__ Xn = (const uint4*)An_g;

  // staging coords: thread loads one uint4 per tile
  int smat = tid >> 8;              // 0 = As, 1 = An
  int sidx = tid & 255;
  int srow = sidx >> 4;             // 0..15
  int scol = sidx & 15;             // 0..15

  for (int t = 0; t < 8; ++t) {
    int grow = ng * 128 + t * 16 + srow;
    if (grow >= N) grow = N - 1;
    const uint4* srcp = smat ? Xn : Xs;
    sT[smat][srow][scol] = srcp[grow * 16 + scol];
    __syncthreads();

    f32x4 acc = {0.f, 0.f, 0.f, 0.f};
    short8 b;
#pragma unroll
    for (int ks = 0; ks < 4; ++ks) {
      b = as_short8(sT[0][l15][ks * 4 + lhi]);
      acc = MFMA16(aH[0][ks], b, acc);
      acc = MFMA16(aL[0][ks], b, acc);
    }
#pragma unroll
    for (int ks = 0; ks < 4; ++ks) {
      b = as_short8(sT[1][l15][ks * 4 + lhi]);
      acc = MFMA16(aH[1][ks], b, acc);
      acc = MFMA16(aL[1][ks], b, acc);
    }

    int rloc = t * 16 + l15;
    int row = ng * 128 + rloc;
    float o0 = fmaxf(acc[0] + bv0, 0.f);
    float o1 = fmaxf(acc[1] + bv1, 0.f);
    float o2 = fmaxf(acc[2] + bv2, 0.f);
    float o3 = fmaxf(acc[3] + bv3, 0.f);
    uint2 st;
    st.x = packbf2(o0, o1);
    st.y = packbf2(o2, o3);
    if (do_fc) {
      ((uint2*)&h2s[rloc][0])[ft * 4 + lhi] = st;
    } else if (row < N) {
      ((uint2*)Out)[row * 32 + ft * 4 + lhi] = st;
    }
    __syncthreads();
  }

  if (do_fc) {
    // FC phase: wave ft handles nodes ng*128 + ft*16 + l15
    short8 fH[3][4], fL[3][4];
#pragma unroll
    for (int ct = 0; ct < 3; ++ct)
#pragma unroll
      for (int ks = 0; ks < 4; ++ks) {
        fH[ct][ks] = as_short8(Wfcp[((0 * 3 + ct) * 4 + ks) * 64 + lane]);
        fL[ct][ks] = as_short8(Wfcp[((1 * 3 + ct) * 4 + ks) * 64 + lane]);
      }
    int rloc = ft * 16 + l15;
    int row = ng * 128 + rloc;
    short8 v0 = as_short8(h2s[rloc][0 * 4 + lhi]);
    short8 v1 = as_short8(h2s[rloc][1 * 4 + lhi]);
    short8 v2 = as_short8(h2s[rloc][2 * 4 + lhi]);
    short8 v3 = as_short8(h2s[rloc][3 * 4 + lhi]);

    f32x4 facc[3];
#pragma unroll
    for (int ct = 0; ct < 3; ++ct) {
      f32x4 a = {0.f, 0.f, 0.f, 0.f};
      a = MFMA16(fH[ct][0], v0, a); a = MFMA16(fL[ct][0], v0, a);
      a = MFMA16(fH[ct][1], v1, a); a = MFMA16(fL[ct][1], v1, a);
      a = MFMA16(fH[ct][2], v2, a); a = MFMA16(fL[ct][2], v2, a);
      a = MFMA16(fH[ct][3], v3, a); a = MFMA16(fL[ct][3], v3, a);
      facc[ct] = a;
    }

    if (row < N) {
      float* orow = OutFC + (size_t)row * 47;
#pragma unroll
      for (int ct = 0; ct < 3; ++ct) {
        int col0 = ct * 16 + lhi * 4;
        if (col0 + 3 < 47) {
          f32x4u stv;
          stv[0] = facc[ct][0] + bfc[col0];
          stv[1] = facc[ct][1] + bfc[col0 + 1];
          stv[2] = facc[ct][2] + bfc[col0 + 2];
          stv[3] = facc[ct][3] + bfc[col0 + 3];
          *(f32x4u*)(orow + col0) = stv;
        } else {
#pragma unroll
          for (int r = 0; r < 4; ++r) {
            int col = col0 + r;
            if (col < 47) orow[col] = facc[ct][r] + bfc[col];
          }
        }
      }
    }
  }
}

// ---------------- launch ----------------

extern "C" void kernel_launch(void* const* d_in, const int* in_sizes, int n_in,
                              void* d_out, int out_size, void* d_ws, size_t ws_size,
                              hipStream_t stream) {
  const float* feat    = (const float*)d_in[0];
  const int*   src     = (const int*)d_in[1];
  const int*   dst     = (const int*)d_in[2];
  const float* Wself0  = (const float*)d_in[3];
  const float* Wneigh0 = (const float*)d_in[4];
  const float* b0      = (const float*)d_in[5];
  const float* Wself1  = (const float*)d_in[6];
  const float* Wneigh1 = (const float*)d_in[7];
  const float* b1      = (const float*)d_in[8];
  const float* Wfc     = (const float*)d_in[9];
  const float* bfc     = (const float*)d_in[10];
  float* out = (float*)d_out;

  // workspace (bytes); overlaps exploit liveness:
  //   gbuf dead after passB -> featb reuses nothing (separate); h2 fully fused away.
  char* w = (char*)d_ws;
  int*   offs    = (int*)(w);                 // (N+1) ints
  int*   bbase   = (int*)(w + 262144);        // NBUCK+1 ints
  int*   histA   = (int*)(w + 266240);        // NBA*NBUCK ints (~157 KB)
  int*   csr     = (int*)(w + 524288);        // E ints -> ends 6,924,288
  uint4* Wpack   = (uint4*)(w + 7340032);     // 17920 uint4 = 280 KB
  uint*  featb   = (uint*)(w + 7864320);      // N*64 uints (bf16)
  uint*  gbuf    = (uint*)(w + 20971520);     // E uints = 6.4 MB, dead after passB
  uint*  hnb     = (uint*)(w + 27787264);     // N*64 uints (bf16)
  uint*  h0b     = (uint*)(w + 41943040);     // N*64 uints (bf16)

  const int N = NN;

  histA_kernel<<<NBA, 1024, 0, stream>>>(dst, histA);
  scanA_kernel<<<1, 256, 0, stream>>>(histA, bbase);
  scatterA_kernel<<<NBA, 1024, 0, stream>>>(src, dst, histA, bbase, gbuf);
  passB_kernel<<<NBUCK, 1024, 0, stream>>>(gbuf, bbase, offs, csr);

  tobf16_kernel<<<(N * 16 + 255) / 256, 256, 0, stream>>>(feat, featb, N * 16);
  packW_kernel<<<70, 256, 0, stream>>>(Wself0, Wneigh0, Wself1, Wneigh1, Wfc, Wpack);

  const int gblocks = (N + 127) / 128;               // 8-wave blocks, 128 nodes each

  agg_kernel<<<(N + 15) / 16, 256, 0, stream>>>(featb, csr, offs, hnb, N);
  gemm_mfma<<<gblocks, 512, 0, stream>>>(featb, hnb, Wpack, b0, h0b,
                                         Wpack + 16384, bfc, out, 0, N);
  agg_kernel<<<(N + 15) / 16, 256, 0, stream>>>(h0b, csr, offs, hnb, N);
  gemm_mfma<<<gblocks, 512, 0, stream>>>(h0b, hnb, Wpack + 8192, b1, h0b,
                                         Wpack + 16384, bfc, out, 1, N);
}

// Round 14
// 179.863 us; speedup vs baseline: 1.4121x; 1.0175x over previous
//
#include <hip/hip_runtime.h>

#define NN 50000
#define NE 1600000
#define NBA 200          // pass-A edge chunks; CPB must be /4
#define CPB (NE / NBA)   // 8000 edges per chunk
#define NBUCK 196        // dst>>8 buckets (256 nodes each); 49999>>8 = 195
#define MAXBE 12288      // per-bucket edge cap: mean 8192, sigma~90 -> +45 sigma
#define TB_BLOCKS 782    // ceil(NN*16 / 1024) for tobf16 role
#define PW_BLOCKS 18     // ceil(17920 / 1024) for packW role

typedef unsigned int uint;
typedef __attribute__((ext_vector_type(8))) short short8;   // 8 bf16 (4 VGPRs)
typedef __attribute__((ext_vector_type(4))) float f32x4;    // MFMA accumulator
typedef __attribute__((ext_vector_type(4), aligned(4))) float f32x4u;  // 4B-aligned store

// ---------------- bf16 helpers (packed pairs in uint32) ----------------

__device__ __forceinline__ uint bf16rne(float f) {
  uint u = __float_as_uint(f);
  return (u + 0x7fffu + ((u >> 16) & 1u)) >> 16;
}
__device__ __forceinline__ uint packbf2(float lo, float hi) {
  return bf16rne(lo) | (bf16rne(hi) << 16);
}
__device__ __forceinline__ float bflo(uint u) { return __uint_as_float(u << 16); }
__device__ __forceinline__ float bfhi(uint u) { return __uint_as_float(u & 0xffff0000u); }

__device__ __forceinline__ short8 as_short8(uint4 v) {
  union { uint4 u; short8 s; } cv; cv.u = v; return cv.s;
}

__device__ __forceinline__ void add8(const uint4 v, float* a) {
  a[0] += bflo(v.x); a[1] += bfhi(v.x);
  a[2] += bflo(v.y); a[3] += bfhi(v.y);
  a[4] += bflo(v.z); a[5] += bfhi(v.z);
  a[6] += bflo(v.w); a[7] += bfhi(v.w);
}

// ---------------- fused prep: hist (blocks [0,NBA)) + tobf16 + packW ------------
// All three are mutually independent; one dispatch fills the machine.
// histAT layout: [bucket][chunk] (transposed) so scanA streams contiguously.

__global__ __launch_bounds__(1024) void prep_kernel(
    const int* __restrict__ dst, int* __restrict__ histAT,
    const float* __restrict__ feat, uint* __restrict__ featb,
    const float* __restrict__ W00, const float* __restrict__ W01,
    const float* __restrict__ W10, const float* __restrict__ W11,
    const float* __restrict__ Wfc, uint4* __restrict__ Wpack) {
  __shared__ int h[NBUCK];
  int tid = threadIdx.x, bid = blockIdx.x;

  if (bid < NBA) {                      // ---- role: bucket histogram ----
    if (tid < NBUCK) h[tid] = 0;
    __syncthreads();
    const int4* d4 = (const int4*)(dst + bid * CPB);
    for (int i = tid; i < CPB / 4; i += 1024) {
      int4 d = d4[i];
      atomicAdd(&h[d.x >> 8], 1);
      atomicAdd(&h[d.y >> 8], 1);
      atomicAdd(&h[d.z >> 8], 1);
      atomicAdd(&h[d.w >> 8], 1);
    }
    __syncthreads();
    if (tid < NBUCK) histAT[tid * NBA + bid] = h[tid];
  } else if (bid < NBA + TB_BLOCKS) {   // ---- role: f32 -> bf16 pack ----
    int t = (bid - NBA) * 1024 + tid;
    if (t < NN * 16) {
      float4 a = ((const float4*)feat)[2 * t];
      float4 b = ((const float4*)feat)[2 * t + 1];
      uint4 o;
      o.x = packbf2(a.x, a.y);
      o.y = packbf2(a.z, a.w);
      o.z = packbf2(b.x, b.y);
      o.w = packbf2(b.z, b.w);
      ((uint4*)featb)[t] = o;
    }
  } else {                              // ---- role: weight fragment pack ----
    int t = (bid - NBA - TB_BLOCKS) * 1024 + tid;
    if (t < 16384) {
      int lane = t & 63;
      int ks   = (t >> 6) & 3;
      int ft   = (t >> 8) & 7;
      int part = (t >> 11) & 1;
      int mat  = (t >> 12) & 1;
      int layer= (t >> 13) & 1;
      const float* Wsrc = layer ? (mat ? W11 : W10) : (mat ? W01 : W00);
      int feat_i = ft * 16 + (lane & 15);
      int kbase = ks * 32 + (lane >> 4) * 8;
      uint o[4];
#pragma unroll
      for (int hh = 0; hh < 4; ++hh) {
        float w0 = Wsrc[(kbase + 2 * hh) * 128 + feat_i];
        float w1 = Wsrc[(kbase + 2 * hh + 1) * 128 + feat_i];
        uint h0 = bf16rne(w0), h1 = bf16rne(w1);
        uint v0, v1;
        if (part == 0) { v0 = h0; v1 = h1; }
        else {
          v0 = bf16rne(w0 - __uint_as_float(h0 << 16));
          v1 = bf16rne(w1 - __uint_as_float(h1 << 16));
        }
        o[hh] = v0 | (v1 << 16);
      }
      uint4 r; r.x = o[0]; r.y = o[1]; r.z = o[2]; r.w = o[3];
      Wpack[t] = r;
    } else if (t < 16384 + 1536) {
      int tt = t - 16384;
      int lane = tt & 63;
      int ks   = (tt >> 6) & 3;
      int ct   = (tt >> 8) % 3;
      int part = tt / 768;
      int col  = ct * 16 + (lane & 15);
      int kbase = ks * 32 + (lane >> 4) * 8;
      uint o[4];
#pragma unroll
      for (int hh = 0; hh < 4; ++hh) {
        float w0 = (col < 47) ? Wfc[(kbase + 2 * hh) * 47 + col] : 0.f;
        float w1 = (col < 47) ? Wfc[(kbase + 2 * hh + 1) * 47 + col] : 0.f;
        uint h0 = bf16rne(w0), h1 = bf16rne(w1);
        uint v0, v1;
        if (part == 0) { v0 = h0; v1 = h1; }
        else {
          v0 = bf16rne(w0 - __uint_as_float(h0 << 16));
          v1 = bf16rne(w1 - __uint_as_float(h1 << 16));
        }
        o[hh] = v0 | (v1 << 16);
      }
      uint4 r; r.x = o[0]; r.y = o[1]; r.z = o[2]; r.w = o[3];
      Wpack[t] = r;
    }
  }
}

// ---------------- scanA: per-bucket cross-chunk exclusive prefix (streamed) -----
// histAT[bucket][chunk]: thread t streams its bucket's 200 ints as 50 int4s.

__global__ __launch_bounds__(256) void scanA_kernel(int* __restrict__ histAT,
                                                    int* __restrict__ bucket_base) {
  __shared__ int wsum[4];
  int t = threadIdx.x;
  int s = 0;
  if (t < NBUCK) {
    int4* row = (int4*)(histAT + t * NBA);
#pragma unroll 10
    for (int b4 = 0; b4 < NBA / 4; ++b4) {
      int4 v = row[b4];
      int4 w;
      w.x = s; s += v.x;
      w.y = s; s += v.y;
      w.z = s; s += v.z;
      w.w = s; s += v.w;
      row[b4] = w;
    }
  }
  int lane = t & 63, wid = t >> 6;
  int x = s;
#pragma unroll
  for (int d = 1; d < 64; d <<= 1) {
    int y = __shfl_up(x, d, 64);
    if (lane >= d) x += y;
  }
  if (lane == 63) wsum[wid] = x;
  __syncthreads();
  int woff = 0;
  if (wid > 0) woff += wsum[0];
  if (wid > 1) woff += wsum[1];
  if (wid > 2) woff += wsum[2];
  int excl = woff + x - s;
  if (t < NBUCK) bucket_base[t] = excl;
  if (t == NBUCK - 1) bucket_base[NBUCK] = excl + s;
}

__global__ __launch_bounds__(1024) void scatterA_kernel(const int* __restrict__ src,
                                                        const int* __restrict__ dst,
                                                        const int* __restrict__ histAT,
                                                        const int* __restrict__ bucket_base,
                                                        uint* __restrict__ gbuf) {
  __shared__ int cur[NBUCK];
  int tid = threadIdx.x, b = blockIdx.x;
  if (tid < NBUCK) cur[tid] = histAT[tid * NBA + b] + bucket_base[tid];
  __syncthreads();
  const int4* d4 = (const int4*)(dst + b * CPB);
  const int4* s4 = (const int4*)(src + b * CPB);
  for (int i = tid; i < CPB / 4; i += 1024) {
    int4 d = d4[i];
    int4 s = s4[i];
    int p0 = atomicAdd(&cur[d.x >> 8], 1);
    int p1 = atomicAdd(&cur[d.y >> 8], 1);
    int p2 = atomicAdd(&cur[d.z >> 8], 1);
    int p3 = atomicAdd(&cur[d.w >> 8], 1);
    gbuf[p0] = (uint)s.x | ((uint)(d.x & 255) << 16);
    gbuf[p1] = (uint)s.y | ((uint)(d.y & 255) << 16);
    gbuf[p2] = (uint)s.z | ((uint)(d.z & 255) << 16);
    gbuf[p3] = (uint)s.w | ((uint)(d.w & 255) << 16);
  }
}

__global__ __launch_bounds__(1024) void passB_kernel(const uint* __restrict__ gbuf,
                                                     const int* __restrict__ bucket_base,
                                                     int* __restrict__ offs,
                                                     int* __restrict__ csr) {
  __shared__ int cnt_l[256];
  __shared__ int cur_l[256];
  __shared__ int wsum[4];
  int tid = threadIdx.x, b = blockIdx.x;
  int bbase = bucket_base[b];
  int nE = bucket_base[b + 1] - bbase;
  int lo = b << 8;
  if (tid < 256) cnt_l[tid] = 0;
  __syncthreads();

  const uint* gptr = gbuf + bbase;
  uint pv[MAXBE / 1024];
#pragma unroll
  for (int j = 0; j < MAXBE / 1024; ++j) {
    int i = tid + j * 1024;
    if (i < nE) {
      uint p = gptr[i];
      pv[j] = p;
      atomicAdd(&cnt_l[(p >> 16) & 255], 1);
    }
  }
  __syncthreads();

  int excl = 0, v = 0;
  if (tid < 256) {
    v = cnt_l[tid];
    int lane = tid & 63, wid = tid >> 6;
    int x = v;
#pragma unroll
    for (int d = 1; d < 64; d <<= 1) {
      int y = __shfl_up(x, d, 64);
      if (lane >= d) x += y;
    }
    if (lane == 63) wsum[wid] = x;
    __syncthreads();
    int woff = 0;
    if (wid > 0) woff += wsum[0];
    if (wid > 1) woff += wsum[1];
    if (wid > 2) woff += wsum[2];
    excl = woff + x - v;
    cur_l[tid] = excl;
    int node = lo + tid;
    if (node <= NN) offs[node] = bbase + excl;   // covers offs[0..NN] across buckets
  } else {
    __syncthreads();
  }
  __syncthreads();

#pragma unroll
  for (int j = 0; j < MAXBE / 1024; ++j) {
    int i = tid + j * 1024;
    if (i < nE) {
      uint p = pv[j];
      int r = atomicAdd(&cur_l[(p >> 16) & 255], 1);
      csr[bbase + r] = (int)(p & 0xFFFFu);
    }
  }
}

// ---------------- segment mean over packed-bf16 rows (proven round-8 form) -------

__global__ __launch_bounds__(256) void agg_kernel(const uint* __restrict__ Xb,
                                                  const int* __restrict__ csr,
                                                  const int* __restrict__ offs,
                                                  uint* __restrict__ outb, int N) {
  const uint4* __restrict__ X4 = (const uint4*)Xb;  // 16 uint4 per 128-dim row
  int tid = threadIdx.x;
  int slot = tid >> 4;
  int lane = tid & 15;
  int n = blockIdx.x * 16 + slot;
  if (n >= N) return;
  int s = offs[n], e = offs[n + 1];

  float aA[8] = {0.f, 0.f, 0.f, 0.f, 0.f, 0.f, 0.f, 0.f};
  float aB[8] = {0.f, 0.f, 0.f, 0.f, 0.f, 0.f, 0.f, 0.f};

  int j = s;
  for (; j + 8 <= e; j += 8) {
    int i0 = csr[j + 0], i1 = csr[j + 1], i2 = csr[j + 2], i3 = csr[j + 3];
    int i4 = csr[j + 4], i5 = csr[j + 5], i6 = csr[j + 6], i7 = csr[j + 7];
    uint4 v0 = X4[i0 * 16 + lane];
    uint4 v1 = X4[i1 * 16 + lane];
    uint4 v2 = X4[i2 * 16 + lane];
    uint4 v3 = X4[i3 * 16 + lane];
    uint4 v4 = X4[i4 * 16 + lane];
    uint4 v5 = X4[i5 * 16 + lane];
    uint4 v6 = X4[i6 * 16 + lane];
    uint4 v7 = X4[i7 * 16 + lane];
    add8(v0, aA); add8(v1, aA); add8(v2, aA); add8(v3, aA);
    add8(v4, aB); add8(v5, aB); add8(v6, aB); add8(v7, aB);
  }
  for (; j < e; ++j) {
    uint4 v = X4[csr[j] * 16 + lane];
    add8(v, aA);
  }

  float inv = 1.0f / fmaxf((float)(e - s), 1.0f);
  uint4 o;
  o.x = packbf2((aA[0] + aB[0]) * inv, (aA[1] + aB[1]) * inv);
  o.y = packbf2((aA[2] + aB[2]) * inv, (aA[3] + aB[3]) * inv);
  o.z = packbf2((aA[4] + aB[4]) * inv, (aA[5] + aB[5]) * inv);
  o.w = packbf2((aA[6] + aB[6]) * inv, (aA[7] + aB[7]) * inv);
  ((uint4*)outb)[n * 16 + lane] = o;
}

// ---------------- MFMA dual-GEMM, LDS-staged, optional fused final FC ------------
// Block = 512 threads = 8 waves = ft 0..7, sharing one 128-node group.
// D layout (m89/m91-verified): col=lane&15 -> node, row=(lane>>4)*4+reg -> feat.

#define MFMA16(a, b, c) __builtin_amdgcn_mfma_f32_16x16x32_bf16((a), (b), (c), 0, 0, 0)

__global__ __launch_bounds__(512) void gemm_mfma(
    const uint* __restrict__ As_g, const uint* __restrict__ An_g,
    const uint4* __restrict__ Wp,   // pre-offset per layer
    const float* __restrict__ bias, uint* __restrict__ Out,
    const uint4* __restrict__ Wfcp, const float* __restrict__ bfc,
    float* __restrict__ OutFC, int do_fc, int N) {
  __shared__ uint4 sT[2][16][17];   // staging: [mat][row][16 uint4 + pad]
  __shared__ uint4 h2s[128][17];    // fused-fc H rows (bf16), padded
  int tid = threadIdx.x;
  int lane = tid & 63;
  int ft = tid >> 6;                // wave id = feat tile
  int ng = blockIdx.x;
  int l15 = lane & 15, lhi = lane >> 4;

  short8 aH[2][4], aL[2][4];
#pragma unroll
  for (int m = 0; m < 2; ++m)
#pragma unroll
    for (int ks = 0; ks < 4; ++ks) {
      aH[m][ks] = as_short8(Wp[(m * 2 + 0) * 2048 + ft * 256 + ks * 64 + lane]);
      aL[m][ks] = as_short8(Wp[(m * 2 + 1) * 2048 + ft * 256 + ks * 64 + lane]);
    }
  int feat0 = ft * 16 + lhi * 4;
  float bv0 = bias[feat0], bv1 = bias[feat0 + 1];
  float bv2 = bias[feat0 + 2], bv3 = bias[feat0 + 3];

  const uint4* __restrict__ Xs = (const uint4*)As_g;
  const uint4* __restrict__ Xn = (const uint4*)An_g;

  int smat = tid >> 8;              // 0 = As, 1 = An
  int sidx = tid & 255;
  int srow = sidx >> 4;             // 0..15
  int scol = sidx & 15;             // 0..15

  for (int t = 0; t < 8; ++t) {
    int grow = ng * 128 + t * 16 + srow;
    if (grow >= N) grow = N - 1;
    const uint4* srcp = smat ? Xn : Xs;
    sT[smat][srow][scol] = srcp[grow * 16 + scol];
    __syncthreads();

    f32x4 acc = {0.f, 0.f, 0.f, 0.f};
    short8 b;
#pragma unroll
    for (int ks = 0; ks < 4; ++ks) {
      b = as_short8(sT[0][l15][ks * 4 + lhi]);
      acc = MFMA16(aH[0][ks], b, acc);
      acc = MFMA16(aL[0][ks], b, acc);
    }
#pragma unroll
    for (int ks = 0; ks < 4; ++ks) {
      b = as_short8(sT[1][l15][ks * 4 + lhi]);
      acc = MFMA16(aH[1][ks], b, acc);
      acc = MFMA16(aL[1][ks], b, acc);
    }

    int rloc = t * 16 + l15;
    int row = ng * 128 + rloc;
    float o0 = fmaxf(acc[0] + bv0, 0.f);
    float o1 = fmaxf(acc[1] + bv1, 0.f);
    float o2 = fmaxf(acc[2] + bv2, 0.f);
    float o3 = fmaxf(acc[3] + bv3, 0.f);
    uint2 st;
    st.x = packbf2(o0, o1);
    st.y = packbf2(o2, o3);
    if (do_fc) {
      ((uint2*)&h2s[rloc][0])[ft * 4 + lhi] = st;
    } else if (row < N) {
      ((uint2*)Out)[row * 32 + ft * 4 + lhi] = st;
    }
    __syncthreads();
  }

  if (do_fc) {
    short8 fH[3][4], fL[3][4];
#pragma unroll
    for (int ct = 0; ct < 3; ++ct)
#pragma unroll
      for (int ks = 0; ks < 4; ++ks) {
        fH[ct][ks] = as_short8(Wfcp[((0 * 3 + ct) * 4 + ks) * 64 + lane]);
        fL[ct][ks] = as_short8(Wfcp[((1 * 3 + ct) * 4 + ks) * 64 + lane]);
      }
    int rloc = ft * 16 + l15;
    int row = ng * 128 + rloc;
    short8 v0 = as_short8(h2s[rloc][0 * 4 + lhi]);
    short8 v1 = as_short8(h2s[rloc][1 * 4 + lhi]);
    short8 v2 = as_short8(h2s[rloc][2 * 4 + lhi]);
    short8 v3 = as_short8(h2s[rloc][3 * 4 + lhi]);

    f32x4 facc[3];
#pragma unroll
    for (int ct = 0; ct < 3; ++ct) {
      f32x4 a = {0.f, 0.f, 0.f, 0.f};
      a = MFMA16(fH[ct][0], v0, a); a = MFMA16(fL[ct][0], v0, a);
      a = MFMA16(fH[ct][1], v1, a); a = MFMA16(fL[ct][1], v1, a);
      a = MFMA16(fH[ct][2], v2, a); a = MFMA16(fL[ct][2], v2, a);
      a = MFMA16(fH[ct][3], v3, a); a = MFMA16(fL[ct][3], v3, a);
      facc[ct] = a;
    }

    if (row < N) {
      float* orow = OutFC + (size_t)row * 47;
#pragma unroll
      for (int ct = 0; ct < 3; ++ct) {
        int col0 = ct * 16 + lhi * 4;
        if (col0 + 3 < 47) {
          f32x4u stv;
          stv[0] = facc[ct][0] + bfc[col0];
          stv[1] = facc[ct][1] + bfc[col0 + 1];
          stv[2] = facc[ct][2] + bfc[col0 + 2];
          stv[3] = facc[ct][3] + bfc[col0 + 3];
          *(f32x4u*)(orow + col0) = stv;
        } else {
#pragma unroll
          for (int r = 0; r < 4; ++r) {
            int col = col0 + r;
            if (col < 47) orow[col] = facc[ct][r] + bfc[col];
          }
        }
      }
    }
  }
}

// ---------------- launch ----------------

extern "C" void kernel_launch(void* const* d_in, const int* in_sizes, int n_in,
                              void* d_out, int out_size, void* d_ws, size_t ws_size,
                              hipStream_t stream) {
  const float* feat    = (const float*)d_in[0];
  const int*   src     = (const int*)d_in[1];
  const int*   dst     = (const int*)d_in[2];
  const float* Wself0  = (const float*)d_in[3];
  const float* Wneigh0 = (const float*)d_in[4];
  const float* b0      = (const float*)d_in[5];
  const float* Wself1  = (const float*)d_in[6];
  const float* Wneigh1 = (const float*)d_in[7];
  const float* b1      = (const float*)d_in[8];
  const float* Wfc     = (const float*)d_in[9];
  const float* bfc     = (const float*)d_in[10];
  float* out = (float*)d_out;

  char* w = (char*)d_ws;
  int*   offs    = (int*)(w);                 // (N+1) ints
  int*   bbase   = (int*)(w + 262144);        // NBUCK+1 ints
  int*   histAT  = (int*)(w + 266240);        // NBUCK*NBA ints (~157 KB)
  int*   csr     = (int*)(w + 524288);        // E ints -> ends 6,924,288
  uint4* Wpack   = (uint4*)(w + 7340032);     // 17920 uint4 = 280 KB
  uint*  featb   = (uint*)(w + 7864320);      // N*64 uints (bf16)
  uint*  gbuf    = (uint*)(w + 20971520);     // E uints = 6.4 MB, dead after passB
  uint*  hnb     = (uint*)(w + 27787264);     // N*64 uints (bf16)
  uint*  h0b     = (uint*)(w + 41943040);     // N*64 uints (bf16)

  const int N = NN;

  prep_kernel<<<NBA + TB_BLOCKS + PW_BLOCKS, 1024, 0, stream>>>(
      dst, histAT, feat, featb, Wself0, Wneigh0, Wself1, Wneigh1, Wfc, Wpack);
  scanA_kernel<<<1, 256, 0, stream>>>(histAT, bbase);
  scatterA_kernel<<<NBA, 1024, 0, stream>>>(src, dst, histAT, bbase, gbuf);
  passB_kernel<<<NBUCK, 1024, 0, stream>>>(gbuf, bbase, offs, csr);

  const int gblocks = (N + 127) / 128;               // 8-wave blocks, 128 nodes each

  agg_kernel<<<(N + 15) / 16, 256, 0, stream>>>(featb, csr, offs, hnb, N);
  gemm_mfma<<<gblocks, 512, 0, stream>>>(featb, hnb, Wpack, b0, h0b,
                                         Wpack + 16384, bfc, out, 0, N);
  agg_kernel<<<(N + 15) / 16, 256, 0, stream>>>(h0b, csr, offs, hnb, N);
  gemm_mfma<<<gblocks, 512, 0, stream>>>(h0b, hnb, Wpack + 8192, b1, h0b,
                                         Wpack + 16384, bfc, out, 1, N);
}